// Round 10
// baseline (54.730 us; speedup 1.0000x reference)
//
#include <hip/hip_runtime.h>
#include <math.h>

#define NB 128
#define NC 8
#define NV 16384
#define NK 64
#define NR 128
#define CH 4    // vertex chunks (of 64) per verts block

// flat output offsets (elements, f32)
#define OFF_MASKS  0
#define OFF_VP     2097152
#define OFF_THETAS 8388608
#define OFF_ALPHAS 8388736
#define OFF_ROT    8388864
#define OFF_SCALES 8389376
#define OFF_DEPTHS 8389504
#define OFF_C2D    8389632
#define OFF_TRANS  8389888
#define OFF_CLP    8390272

#define PI_F     3.14159265358979323846f
#define TWOPI_F  6.28318530717958647692f

// d_ws layout:
//   Wi[0..8]        scnt: class prefix over records
//   Wi[16..24]      cts:  class prefix over col-tiles (ceil(n_c/5) each)
//   Wi[32+r]        record -> batch id (class-sorted, r = 0..127)
//   Wf[256+r*8]     params per record: scale,qw,qy,tx,ty,tz,feff,pad
//   Wf[1280...]     Bpack (ushort): per (coltile t, kstep ks): 512 bf16
//                   elem (t*2+ks)*512 + lane*8 + j <-> B[col=lane&15][k=ks*32+(lane>>4)*8+j]

typedef short  short8 __attribute__((ext_vector_type(8)));
typedef float  f32x4  __attribute__((ext_vector_type(4)));

__device__ __forceinline__ unsigned short f2bf(float f) {
  unsigned int u = __float_as_uint(f);
  unsigned int r = (u + 0x7FFFu + ((u >> 16) & 1u)) >> 16;   // RNE
  return (unsigned short)r;
}

// ---- kernel 1: scalars + tables + bf16 B-pack (17 blocks) -------------------
__global__ __launch_bounds__(256) void prep_kernel(
    const float* __restrict__ roi, const float* __restrict__ focals,
    const float* __restrict__ td,  const float* __restrict__ t2,
    const float* __restrict__ ls,  const float* __restrict__ ld,
    const float* __restrict__ cp,  const float* __restrict__ fc,
    float* __restrict__ out, int* __restrict__ Wi, float* __restrict__ Wf) {
  int tid = threadIdx.x;
  int bx  = blockIdx.x;

  __shared__ int cls_sh[NB];
  __shared__ int rb_sh[NB];
  __shared__ int scnt_sh[NC + 1];
  __shared__ int cts_sh[NC + 1];

  int b = tid;
  int cls = 0;
  if (b < NB) {
    float pmax = cp[b * NC];
    for (int c = 1; c < NC; ++c) {
      float pv = cp[b * NC + c];
      if (pv > pmax) { pmax = pv; cls = c; }
    }
    cls_sh[b] = cls;
  }
  __syncthreads();
  if (tid <= NC) {
    int cnt = 0;
    for (int j = 0; j < NB; ++j) cnt += (cls_sh[j] < tid);
    scnt_sh[tid] = cnt;
  }
  __syncthreads();
  if (tid == 0) {
    cts_sh[0] = 0;
    for (int c = 0; c < NC; ++c) {
      int n = scnt_sh[c + 1] - scnt_sh[c];
      cts_sh[c + 1] = cts_sh[c] + (n + 4) / 5;
    }
  }
  int rank = 0;
  if (b < NB) {
    rank = scnt_sh[cls];
    for (int j = 0; j < b; ++j) rank += (cls_sh[j] == cls);
    rb_sh[rank] = b;
  }
  __syncthreads();

  if (bx == 0) {
    if (b < NB) {
      float r0 = roi[b * 4 + 0], r1 = roi[b * 4 + 1];
      float r2 = roi[b * 4 + 2], r3 = roi[b * 4 + 3];
      float dx = r2 - r0, dy = r3 - r1;
      float mx = 0.5f * (r2 + r0), my = 0.5f * (r3 + r1);
      float theta = atan2f(td[b * 2 + 1], td[b * 2 + 0]);
      float qw = cosf(0.5f * theta);
      float qy = sinf(0.5f * theta);
      float area  = dx * dy;
      float scale = expf(ls[b]);
      float depth = sqrtf(expf(ld[b]) / area);
      float cx = mx + t2[b * 2 + 0] * dx;
      float cy = my + t2[b * 2 + 1] * dy;
      float tux = cy, tuy = -cx;
      float n = sqrtf(tux * tux + tuy * tuy + 1.0f);
      float tx_ = depth * (tux / n);
      float ty_ = depth * (tuy / n);
      float tz_ = depth * (-1.0f / n);
      float alpha = -(theta - atanf(tx_ / tz_));
      float a  = alpha + PI_F;
      float rr = fmodf(a, TWOPI_F);
      if (rr < 0.0f) rr += TWOPI_F;
      float alpha_out = rr - PI_F;
      float pmax = cp[b * NC];
      for (int c = 1; c < NC; ++c) pmax = fmaxf(pmax, cp[b * NC + c]);
      float feff = 2.0f * focals[b] / (float)NR;

      out[OFF_THETAS + b]      = theta;
      out[OFF_ALPHAS + b]      = alpha_out;
      out[OFF_ROT + 4 * b + 0] = qw;
      out[OFF_ROT + 4 * b + 1] = 0.0f;
      out[OFF_ROT + 4 * b + 2] = qy;
      out[OFF_ROT + 4 * b + 3] = 0.0f;
      out[OFF_SCALES + b]      = scale;
      out[OFF_DEPTHS + b]      = depth;
      out[OFF_C2D + 2 * b + 0] = cx;
      out[OFF_C2D + 2 * b + 1] = cy;
      out[OFF_TRANS + 3 * b + 0] = tx_;
      out[OFF_TRANS + 3 * b + 1] = ty_;
      out[OFF_TRANS + 3 * b + 2] = tz_;
      out[OFF_CLP + b]         = logf(pmax);

      float* par = Wf + 256 + rank * 8;
      par[0] = scale; par[1] = qw; par[2] = qy; par[3] = tx_;
      par[4] = ty_;   par[5] = tz_; par[6] = feff; par[7] = 0.0f;
      Wi[32 + rank] = b;
    }
    if (tid <= NC) {
      Wi[tid]      = scnt_sh[tid];
      Wi[16 + tid] = cts_sh[tid];
    }
  } else {
    // blocks 1..16: pack coeffs into bf16 B-fragments
    unsigned short* BPu = (unsigned short*)(Wf + 1280);
    int total = cts_sh[NC] * 1024;      // elements
    for (int g = (bx - 1) * 256 + tid; g < total; g += 16 * 256) {
      int t   = g >> 10;
      int r10 = g & 1023;
      int ks  = r10 >> 9;
      int li  = (r10 >> 3) & 63;
      int j   = r10 & 7;
      int col = li & 15, kg = li >> 4;
      int k   = ks * 32 + kg * 8 + j;
      int c = 0;
      while (!(t >= cts_sh[c] && t < cts_sh[c + 1])) ++c;
      int local_ct = t - cts_sh[c];
      int n_c = scnt_sh[c + 1] - scnt_sh[c];
      float val = 0.0f;
      if (col < 15) {
        int lr = col / 3, comp = col - 3 * lr;
        int lrec = local_ct * 5 + lr;
        if (lrec < n_c) {
          int bb = rb_sh[scnt_sh[c] + lrec];
          val = fc[((size_t)(bb * NC + c) * NK + k) * 3 + comp];
        }
      }
      BPu[(size_t)g] = f2bf(val);
    }
  }
}

// ---- kernel 2: per-class GEMM + transform, register-pipelined chunks --------
// grid (64, 8): x = 256-vertex super-tile (4 chunks of 64), y = class.
// 4 waves/block. Chunk i+1's global loads issue before chunk i's compute,
// keeping ~7 KB/wave outstanding under the LDS/MFMA phases (latency hiding).
__global__ __launch_bounds__(256) void verts_kernel(
    const float* __restrict__ basev,    // (C, V, 3)
    const float* __restrict__ basis,    // (C, V, K)
    const int*   __restrict__ Wi,
    const float* __restrict__ Wf,
    float* __restrict__ out) {
  int c   = blockIdx.y;
  int ct0 = Wi[16 + c], ct1 = Wi[16 + c + 1];
  if (ct0 >= ct1) return;
  int rec0  = Wi[c];
  int nrecs = Wi[c + 1] - rec0;

  __shared__ unsigned short s_B[8 * 1024];   // up to 8 staged col-tiles (16 KB)
  __shared__ float s_vp[4][256];             // per-wave store staging (4 KB)

  int ntile = ct1 - ct0;
  if (ntile > 8) ntile = 8;
  {
    const uint4* Bg = (const uint4*)((const unsigned short*)(Wf + 1280) +
                                     (size_t)ct0 * 1024);
    uint4* Bs = (uint4*)s_B;
    for (int i = threadIdx.x; i < ntile * 128; i += 256) Bs[i] = Bg[i];
  }

  int wave = threadIdx.x >> 6;
  int lane = threadIdx.x & 63;
  int row  = lane & 15, kg = lane >> 4;
  int vwave = blockIdx.x * (64 * CH) + wave * 16;   // wave's 16-row base, chunk 0

  // epilogue lane roles: q -> (record lr, component comp); rowg -> vertex group
  int q = lane & 15, rowg = lane >> 4;
  int lr = q / 3, comp = q - 3 * lr;
  bool qok = (q < 15);
  int sbase = lane & 48;
  int sx = sbase | (qok ? 3 * lr     : 0);
  int sy = sbase | (qok ? 3 * lr + 1 : 0);
  int sz = sbase | (qok ? 3 * lr + 2 : 0);
  // readout lane roles
  int rrec = lane / 12;            // 0..4 (lanes >= 60 idle)
  int roff = (lane % 12) * 4;      // float4 offset within the record's 48

  // double-buffered chunk inputs (static indices after full unroll)
  float4 aL[2][4];
  float  bxL[2][4], byL[2][4], bzL[2][4];

#define LOADCH(buf, ch_) {                                                     \
    int v0_ = vwave + (ch_) * 64;                                              \
    const float* ab = basis + ((size_t)c * NV + v0_ + row) * NK + kg * 8;      \
    aL[buf][0] = *(const float4*)(ab);                                         \
    aL[buf][1] = *(const float4*)(ab + 4);                                     \
    aL[buf][2] = *(const float4*)(ab + 32);                                    \
    aL[buf][3] = *(const float4*)(ab + 36);                                    \
    _Pragma("unroll")                                                          \
    for (int j = 0; j < 4; ++j) {                                              \
      const float* bp = basev + ((size_t)c * NV + v0_ + rowg * 4 + j) * 3;     \
      bxL[buf][j] = bp[0]; byL[buf][j] = bp[1]; bzL[buf][j] = bp[2];           \
    } }

  LOADCH(0, 0)

  __syncthreads();   // s_B staged (only barrier in the kernel)

#pragma unroll
  for (int ch = 0; ch < CH; ++ch) {
    if (ch + 1 < CH) LOADCH((ch + 1) & 1, ch + 1)   // prefetch next chunk
    const int cur = ch & 1;
    int v0 = vwave + ch * 64;

    short8 A0, A1;
    A0[0]=f2bf(aL[cur][0].x); A0[1]=f2bf(aL[cur][0].y); A0[2]=f2bf(aL[cur][0].z); A0[3]=f2bf(aL[cur][0].w);
    A0[4]=f2bf(aL[cur][1].x); A0[5]=f2bf(aL[cur][1].y); A0[6]=f2bf(aL[cur][1].z); A0[7]=f2bf(aL[cur][1].w);
    A1[0]=f2bf(aL[cur][2].x); A1[1]=f2bf(aL[cur][2].y); A1[2]=f2bf(aL[cur][2].z); A1[3]=f2bf(aL[cur][2].w);
    A1[4]=f2bf(aL[cur][3].x); A1[5]=f2bf(aL[cur][3].y); A1[6]=f2bf(aL[cur][3].z); A1[7]=f2bf(aL[cur][3].w);

    for (int t = ct0; t < ct1; ++t) {
      short8 B0, B1;
      if (t - ct0 < 8) {
        B0 = *(short8*)&s_B[(size_t)(t - ct0) * 1024 + lane * 8];
        B1 = *(short8*)&s_B[(size_t)(t - ct0) * 1024 + 512 + lane * 8];
      } else {
        const float4* BP4 = (const float4*)(Wf + 1280);
        float4 rb0 = BP4[(size_t)(t * 2 + 0) * 64 + lane];
        float4 rb1 = BP4[(size_t)(t * 2 + 1) * 64 + lane];
        B0 = *(short8*)&rb0; B1 = *(short8*)&rb1;
      }
      f32x4 acc = {0.0f, 0.0f, 0.0f, 0.0f};
      acc = __builtin_amdgcn_mfma_f32_16x16x32_bf16(A0, B0, acc, 0, 0, 0);
      acc = __builtin_amdgcn_mfma_f32_16x16x32_bf16(A1, B1, acc, 0, 0, 0);

      int nrec_ct = nrecs - (t - ct0) * 5;
      nrec_ct = (nrec_ct > 5) ? 5 : nrec_ct;
      bool valid = qok && (lr < nrec_ct);
      int rec = rec0 + (t - ct0) * 5 + (valid ? lr : 0);
      float4 P0 = *(const float4*)(Wf + 256 + rec * 8);
      float4 P1 = *(const float4*)(Wf + 256 + rec * 8 + 4);
      float scale = P0.x, qw = P0.y, qy = P0.z, tx = P0.w;
      float ty = P1.x, tz = P1.y, feff = P1.z;

#pragma unroll
      for (int j = 0; j < 4; ++j) {
        float dx_ = __shfl(acc[j], sx);
        float dy_ = __shfl(acc[j], sy);
        float dz_ = __shfl(acc[j], sz);

        float vx = (bxL[cur][j] + dx_) * scale;
        float vy = (byL[cur][j] + dy_) * scale;
        float vz = (bzL[cur][j] + dz_) * scale;
        float t2x = 2.0f * qy * vz;
        float t2z = -2.0f * qy * vx;
        float rx = vx + qw * t2x + qy * t2z;
        float ry = vy;
        float rz = vz + qw * t2z - qy * t2x;
        float wx = rx + tx, wy = ry + ty, wz = rz + tz;

        float zv = wz;
        float zsafe = (zv > -1e-4f) ? -1e-4f : zv;
        float inv = feff / (-zsafe);
        float px = (wx * inv * 0.5f + 0.5f) * (float)NR;
        float py = (wy * inv * 0.5f + 0.5f) * (float)NR;

        float ov = (comp == 0) ? px : ((comp == 1) ? py : -zv);
        if (qok) s_vp[wave][lr * 48 + (rowg * 4 + j) * 3 + comp] = ov;
      }
      // in-order per-wave DS: reads below see the writes above (no barrier)
      if (lane < 60 && rrec < nrec_ct) {
        float4 val = *(float4*)&s_vp[wave][rrec * 48 + roff];
        int rrec_g = rec0 + (t - ct0) * 5 + rrec;
        int bb = Wi[32 + rrec_g];
        *(float4*)&out[OFF_VP + ((size_t)bb * NV + v0) * 3 + roff] = val;
      }
    }
  }
#undef LOADCH
}

// ---- kernel 3: batch-major mask build, 1024 threads, float4-coalesced -------
__global__ __launch_bounds__(1024) void mask_kernel(float* __restrict__ out) {
  int b   = blockIdx.x;
  int tid = threadIdx.x;
  __shared__ float m[NR * NR];   // 64 KB
  float4 z4; z4.x = 0.0f; z4.y = 0.0f; z4.z = 0.0f; z4.w = 0.0f;
#pragma unroll
  for (int i = 0; i < 4; ++i) ((float4*)m)[tid + i * 1024] = z4;
  __syncthreads();
  const float4* vb4 = (const float4*)(out + OFF_VP + (size_t)b * NV * 3);
#pragma unroll
  for (int i = 0; i < 4; ++i) {
    int g = tid + i * 1024;              // vertex group of 4 (floats 12g..12g+11)
    float4 w0 = vb4[3 * g + 0];
    float4 w1 = vb4[3 * g + 1];
    float4 w2 = vb4[3 * g + 2];
    // pairs: (w0.x,w0.y) (w0.w,w1.x) (w1.z,w1.w) (w2.y,w2.z)
    float pxs0 = w0.x, pys0 = w0.y;
    float pxs1 = w0.w, pys1 = w1.x;
    float pxs2 = w1.z, pys2 = w1.w;
    float pxs3 = w2.y, pys3 = w2.z;
    int xi, yi;
    xi = (int)fminf(fmaxf(pxs0, 0.0f), 127.0f);
    yi = (int)fminf(fmaxf(pys0, 0.0f), 127.0f);
    m[yi * NR + xi] = 1.0f;
    xi = (int)fminf(fmaxf(pxs1, 0.0f), 127.0f);
    yi = (int)fminf(fmaxf(pys1, 0.0f), 127.0f);
    m[yi * NR + xi] = 1.0f;
    xi = (int)fminf(fmaxf(pxs2, 0.0f), 127.0f);
    yi = (int)fminf(fmaxf(pys2, 0.0f), 127.0f);
    m[yi * NR + xi] = 1.0f;
    xi = (int)fminf(fmaxf(pxs3, 0.0f), 127.0f);
    yi = (int)fminf(fmaxf(pys3, 0.0f), 127.0f);
    m[yi * NR + xi] = 1.0f;
  }
  __syncthreads();
  float4* mo = (float4*)(out + OFF_MASKS + ((size_t)b << 14));
#pragma unroll
  for (int i = 0; i < 4; ++i) mo[tid + i * 1024] = ((float4*)m)[tid + i * 1024];
}

extern "C" void kernel_launch(void* const* d_in, const int* in_sizes, int n_in,
                              void* d_out, int out_size, void* d_ws, size_t ws_size,
                              hipStream_t stream) {
  const float* roi    = (const float*)d_in[0];
  const float* focals = (const float*)d_in[1];
  const float* td     = (const float*)d_in[2];
  const float* t2     = (const float*)d_in[3];
  const float* ls     = (const float*)d_in[4];
  const float* ld     = (const float*)d_in[5];
  const float* cp     = (const float*)d_in[6];
  const float* fc     = (const float*)d_in[7];
  const float* bv     = (const float*)d_in[8];
  const float* fb     = (const float*)d_in[9];
  float* out = (float*)d_out;
  int*   Wi  = (int*)d_ws;
  float* Wf  = (float*)d_ws;

  prep_kernel<<<dim3(17), dim3(256), 0, stream>>>(
      roi, focals, td, t2, ls, ld, cp, fc, out, Wi, Wf);
  verts_kernel<<<dim3(NV / (64 * CH), NC), dim3(256), 0, stream>>>(
      bv, fb, Wi, Wf, out);
  mask_kernel<<<dim3(NB), dim3(1024), 0, stream>>>(out);
}

// Round 11
// 45.878 us; speedup vs baseline: 1.1929x; 1.1929x over previous
//
#include <hip/hip_runtime.h>
#include <math.h>

#define NB 128
#define NC 8
#define NV 16384
#define NK 64
#define NR 128

// flat output offsets (elements, f32)
#define OFF_MASKS  0
#define OFF_VP     2097152
#define OFF_THETAS 8388608
#define OFF_ALPHAS 8388736
#define OFF_ROT    8388864
#define OFF_SCALES 8389376
#define OFF_DEPTHS 8389504
#define OFF_C2D    8389632
#define OFF_TRANS  8389888
#define OFF_CLP    8390272

#define PI_F     3.14159265358979323846f
#define TWOPI_F  6.28318530717958647692f

// d_ws layout:
//   Wi[0..8]        scnt: class prefix over records
//   Wi[16..24]      cts:  class prefix over col-tiles (ceil(n_c/5) each)
//   Wi[32+r]        record -> batch id (class-sorted, r = 0..127)
//   Wf[256+r*8]     params per record: scale,qw,qy,tx,ty,tz,feff,pad
//   Wf[1280...]     Bpack (ushort): per (coltile t, kstep ks): 512 bf16
//                   elem (t*2+ks)*512 + lane*8 + j <-> B[col=lane&15][k=ks*32+(lane>>4)*8+j]

typedef short  short8 __attribute__((ext_vector_type(8)));
typedef float  f32x4  __attribute__((ext_vector_type(4)));

__device__ __forceinline__ unsigned short f2bf(float f) {
  unsigned int u = __float_as_uint(f);
  unsigned int r = (u + 0x7FFFu + ((u >> 16) & 1u)) >> 16;   // RNE
  return (unsigned short)r;
}

// ---- kernel 1: scalars + tables + bf16 B-pack (17 blocks) -------------------
__global__ __launch_bounds__(256) void prep_kernel(
    const float* __restrict__ roi, const float* __restrict__ focals,
    const float* __restrict__ td,  const float* __restrict__ t2,
    const float* __restrict__ ls,  const float* __restrict__ ld,
    const float* __restrict__ cp,  const float* __restrict__ fc,
    float* __restrict__ out, int* __restrict__ Wi, float* __restrict__ Wf) {
  int tid = threadIdx.x;
  int bx  = blockIdx.x;

  __shared__ int cls_sh[NB];
  __shared__ int rb_sh[NB];
  __shared__ int scnt_sh[NC + 1];
  __shared__ int cts_sh[NC + 1];

  int b = tid;
  int cls = 0;
  if (b < NB) {
    float pmax = cp[b * NC];
    for (int c = 1; c < NC; ++c) {
      float pv = cp[b * NC + c];
      if (pv > pmax) { pmax = pv; cls = c; }
    }
    cls_sh[b] = cls;
  }
  __syncthreads();
  if (tid <= NC) {
    int cnt = 0;
    for (int j = 0; j < NB; ++j) cnt += (cls_sh[j] < tid);
    scnt_sh[tid] = cnt;
  }
  __syncthreads();
  if (tid == 0) {
    cts_sh[0] = 0;
    for (int c = 0; c < NC; ++c) {
      int n = scnt_sh[c + 1] - scnt_sh[c];
      cts_sh[c + 1] = cts_sh[c] + (n + 4) / 5;
    }
  }
  int rank = 0;
  if (b < NB) {
    rank = scnt_sh[cls];
    for (int j = 0; j < b; ++j) rank += (cls_sh[j] == cls);
    rb_sh[rank] = b;
  }
  __syncthreads();

  if (bx == 0) {
    if (b < NB) {
      float r0 = roi[b * 4 + 0], r1 = roi[b * 4 + 1];
      float r2 = roi[b * 4 + 2], r3 = roi[b * 4 + 3];
      float dx = r2 - r0, dy = r3 - r1;
      float mx = 0.5f * (r2 + r0), my = 0.5f * (r3 + r1);
      float theta = atan2f(td[b * 2 + 1], td[b * 2 + 0]);
      float qw = cosf(0.5f * theta);
      float qy = sinf(0.5f * theta);
      float area  = dx * dy;
      float scale = expf(ls[b]);
      float depth = sqrtf(expf(ld[b]) / area);
      float cx = mx + t2[b * 2 + 0] * dx;
      float cy = my + t2[b * 2 + 1] * dy;
      float tux = cy, tuy = -cx;
      float n = sqrtf(tux * tux + tuy * tuy + 1.0f);
      float tx_ = depth * (tux / n);
      float ty_ = depth * (tuy / n);
      float tz_ = depth * (-1.0f / n);
      float alpha = -(theta - atanf(tx_ / tz_));
      float a  = alpha + PI_F;
      float rr = fmodf(a, TWOPI_F);
      if (rr < 0.0f) rr += TWOPI_F;
      float alpha_out = rr - PI_F;
      float pmax = cp[b * NC];
      for (int c = 1; c < NC; ++c) pmax = fmaxf(pmax, cp[b * NC + c]);
      float feff = 2.0f * focals[b] / (float)NR;

      out[OFF_THETAS + b]      = theta;
      out[OFF_ALPHAS + b]      = alpha_out;
      out[OFF_ROT + 4 * b + 0] = qw;
      out[OFF_ROT + 4 * b + 1] = 0.0f;
      out[OFF_ROT + 4 * b + 2] = qy;
      out[OFF_ROT + 4 * b + 3] = 0.0f;
      out[OFF_SCALES + b]      = scale;
      out[OFF_DEPTHS + b]      = depth;
      out[OFF_C2D + 2 * b + 0] = cx;
      out[OFF_C2D + 2 * b + 1] = cy;
      out[OFF_TRANS + 3 * b + 0] = tx_;
      out[OFF_TRANS + 3 * b + 1] = ty_;
      out[OFF_TRANS + 3 * b + 2] = tz_;
      out[OFF_CLP + b]         = logf(pmax);

      float* par = Wf + 256 + rank * 8;
      par[0] = scale; par[1] = qw; par[2] = qy; par[3] = tx_;
      par[4] = ty_;   par[5] = tz_; par[6] = feff; par[7] = 0.0f;
      Wi[32 + rank] = b;
    }
    if (tid <= NC) {
      Wi[tid]      = scnt_sh[tid];
      Wi[16 + tid] = cts_sh[tid];
    }
  } else {
    // blocks 1..16: pack coeffs into bf16 B-fragments
    unsigned short* BPu = (unsigned short*)(Wf + 1280);
    int total = cts_sh[NC] * 1024;      // elements
    for (int g = (bx - 1) * 256 + tid; g < total; g += 16 * 256) {
      int t   = g >> 10;
      int r10 = g & 1023;
      int ks  = r10 >> 9;
      int li  = (r10 >> 3) & 63;
      int j   = r10 & 7;
      int col = li & 15, kg = li >> 4;
      int k   = ks * 32 + kg * 8 + j;
      int c = 0;
      while (!(t >= cts_sh[c] && t < cts_sh[c + 1])) ++c;
      int local_ct = t - cts_sh[c];
      int n_c = scnt_sh[c + 1] - scnt_sh[c];
      float val = 0.0f;
      if (col < 15) {
        int lr = col / 3, comp = col - 3 * lr;
        int lrec = local_ct * 5 + lr;
        if (lrec < n_c) {
          int bb = rb_sh[scnt_sh[c] + lrec];
          val = fc[((size_t)(bb * NC + c) * NK + k) * 3 + comp];
        }
      }
      BPu[(size_t)g] = f2bf(val);
    }
  }
}

// ---- kernel 2: per-class GEMM, DENSE-staged A through LDS -------------------
// grid (256, 8): x = 64-vertex super-tile, y = class. 4 waves/block.
// A-tile (64 rows x 64 K) read with fully-coalesced 64 B/thread loads,
// converted to bf16 during staging, fragments served from LDS (padded stride).
__global__ __launch_bounds__(256) void verts_kernel(
    const float* __restrict__ basev,    // (C, V, 3)
    const float* __restrict__ basis,    // (C, V, K)
    const int*   __restrict__ Wi,
    const float* __restrict__ Wf,
    float* __restrict__ out) {
  int c   = blockIdx.y;
  int ct0 = Wi[16 + c], ct1 = Wi[16 + c + 1];
  if (ct0 >= ct1) return;
  int rec0  = Wi[c];
  int nrecs = Wi[c + 1] - rec0;

  __shared__ unsigned short s_A[64 * 72];    // 9216 B, stride 72 shorts (pad)
  __shared__ float s_bv[192];                // 768 B: basev rows of this tile
  __shared__ unsigned short s_B[8 * 1024];   // up to 8 staged col-tiles (16 KB)
  __shared__ float s_vp[4][256];             // per-wave store staging (4 KB)

  int v0_blk = blockIdx.x * 64;
  {
    // dense A stage: thread t reads 64 contiguous bytes of basis (coalesced)
    int t  = threadIdx.x;
    int r  = t >> 2;               // 0..63
    int c0 = (t & 3) * 16;         // 0,16,32,48
    const float4* src = (const float4*)(basis + ((size_t)c * NV + v0_blk + r) * NK + c0);
    float4 f0 = src[0], f1 = src[1], f2 = src[2], f3 = src[3];
    short8 lo, hi;
    lo[0]=(short)f2bf(f0.x); lo[1]=(short)f2bf(f0.y); lo[2]=(short)f2bf(f0.z); lo[3]=(short)f2bf(f0.w);
    lo[4]=(short)f2bf(f1.x); lo[5]=(short)f2bf(f1.y); lo[6]=(short)f2bf(f1.z); lo[7]=(short)f2bf(f1.w);
    hi[0]=(short)f2bf(f2.x); hi[1]=(short)f2bf(f2.y); hi[2]=(short)f2bf(f2.z); hi[3]=(short)f2bf(f2.w);
    hi[4]=(short)f2bf(f3.x); hi[5]=(short)f2bf(f3.y); hi[6]=(short)f2bf(f3.z); hi[7]=(short)f2bf(f3.w);
    unsigned short* dst = s_A + r * 72 + c0;
    *(short8*)(dst)     = lo;
    *(short8*)(dst + 8) = hi;
    // dense basev stage: 48 float4 = 768 B
    if (t < 48)
      ((float4*)s_bv)[t] = ((const float4*)(basev + ((size_t)c * NV + v0_blk) * 3))[t];
  }

  int ntile = ct1 - ct0;
  if (ntile > 8) ntile = 8;
  {
    const uint4* Bg = (const uint4*)((const unsigned short*)(Wf + 1280) +
                                     (size_t)ct0 * 1024);
    uint4* Bs = (uint4*)s_B;
    for (int i = threadIdx.x; i < ntile * 128; i += 256) Bs[i] = Bg[i];
  }

  int wave = threadIdx.x >> 6;
  int lane = threadIdx.x & 63;
  int v0   = v0_blk + wave * 16;
  int row  = lane & 15, kg = lane >> 4;

  __syncthreads();   // s_A, s_bv, s_B staged

  // A fragments from LDS (padded stride -> ~4-way conflicts max)
  const unsigned short* arow = s_A + (wave * 16 + row) * 72;
  short8 A0 = *(const short8*)(arow + kg * 8);
  short8 A1 = *(const short8*)(arow + 32 + kg * 8);

  // epilogue lane roles: q -> (record lr, component comp); rowg -> vertex group
  int q = lane & 15, rowg = lane >> 4;
  int lr = q / 3, comp = q - 3 * lr;
  bool qok = (q < 15);
  float bvx[4], bvy[4], bvz[4];
#pragma unroll
  for (int j = 0; j < 4; ++j) {
    int wv = wave * 16 + rowg * 4 + j;
    bvx[j] = s_bv[wv * 3 + 0]; bvy[j] = s_bv[wv * 3 + 1]; bvz[j] = s_bv[wv * 3 + 2];
  }
  int sbase = lane & 48;
  int sx = sbase | (qok ? 3 * lr     : 0);
  int sy = sbase | (qok ? 3 * lr + 1 : 0);
  int sz = sbase | (qok ? 3 * lr + 2 : 0);

  // readout lane roles
  int rrec = lane / 12;            // 0..4 (lanes >= 60 idle)
  int roff = (lane % 12) * 4;      // float4 offset within the record's 48

  for (int t = ct0; t < ct1; ++t) {
    short8 B0, B1;
    if (t - ct0 < 8) {
      B0 = *(short8*)&s_B[(size_t)(t - ct0) * 1024 + lane * 8];
      B1 = *(short8*)&s_B[(size_t)(t - ct0) * 1024 + 512 + lane * 8];
    } else {
      const float4* BP4 = (const float4*)(Wf + 1280);
      float4 rb0 = BP4[(size_t)(t * 2 + 0) * 64 + lane];
      float4 rb1 = BP4[(size_t)(t * 2 + 1) * 64 + lane];
      B0 = *(short8*)&rb0; B1 = *(short8*)&rb1;
    }
    f32x4 acc = {0.0f, 0.0f, 0.0f, 0.0f};
    acc = __builtin_amdgcn_mfma_f32_16x16x32_bf16(A0, B0, acc, 0, 0, 0);
    acc = __builtin_amdgcn_mfma_f32_16x16x32_bf16(A1, B1, acc, 0, 0, 0);

    int nrec_ct = nrecs - (t - ct0) * 5;
    nrec_ct = (nrec_ct > 5) ? 5 : nrec_ct;
    bool valid = qok && (lr < nrec_ct);
    int rec = rec0 + (t - ct0) * 5 + (valid ? lr : 0);
    float4 P0 = *(const float4*)(Wf + 256 + rec * 8);
    float4 P1 = *(const float4*)(Wf + 256 + rec * 8 + 4);
    float scale = P0.x, qw = P0.y, qy = P0.z, tx = P0.w;
    float ty = P1.x, tz = P1.y, feff = P1.z;

#pragma unroll
    for (int j = 0; j < 4; ++j) {
      float dx_ = __shfl(acc[j], sx);
      float dy_ = __shfl(acc[j], sy);
      float dz_ = __shfl(acc[j], sz);

      float vx = (bvx[j] + dx_) * scale;
      float vy = (bvy[j] + dy_) * scale;
      float vz = (bvz[j] + dz_) * scale;
      float t2x = 2.0f * qy * vz;
      float t2z = -2.0f * qy * vx;
      float rx = vx + qw * t2x + qy * t2z;
      float ry = vy;
      float rz = vz + qw * t2z - qy * t2x;
      float wx = rx + tx, wy = ry + ty, wz = rz + tz;

      float zv = wz;
      float zsafe = (zv > -1e-4f) ? -1e-4f : zv;
      float inv = feff / (-zsafe);
      float px = (wx * inv * 0.5f + 0.5f) * (float)NR;
      float py = (wy * inv * 0.5f + 0.5f) * (float)NR;

      float ov = (comp == 0) ? px : ((comp == 1) ? py : -zv);
      if (qok) s_vp[wave][lr * 48 + (rowg * 4 + j) * 3 + comp] = ov;
    }
    // in-order per-wave DS: reads below see the writes above (no barrier)
    if (lane < 60 && rrec < nrec_ct) {
      float4 val = *(float4*)&s_vp[wave][rrec * 48 + roff];
      int rrec_g = rec0 + (t - ct0) * 5 + rrec;
      int bb = Wi[32 + rrec_g];
      *(float4*)&out[OFF_VP + ((size_t)bb * NV + v0) * 3 + roff] = val;
    }
  }
}

// ---- kernel 3: batch-major mask build, 1024 threads, float4-coalesced -------
__global__ __launch_bounds__(1024) void mask_kernel(float* __restrict__ out) {
  int b   = blockIdx.x;
  int tid = threadIdx.x;
  __shared__ float m[NR * NR];   // 64 KB
  float4 z4; z4.x = 0.0f; z4.y = 0.0f; z4.z = 0.0f; z4.w = 0.0f;
#pragma unroll
  for (int i = 0; i < 4; ++i) ((float4*)m)[tid + i * 1024] = z4;
  __syncthreads();
  const float4* vb4 = (const float4*)(out + OFF_VP + (size_t)b * NV * 3);
#pragma unroll
  for (int i = 0; i < 4; ++i) {
    int g = tid + i * 1024;              // vertex group of 4 (floats 12g..12g+11)
    float4 w0 = vb4[3 * g + 0];
    float4 w1 = vb4[3 * g + 1];
    float4 w2 = vb4[3 * g + 2];
    // pairs: (w0.x,w0.y) (w0.w,w1.x) (w1.z,w1.w) (w2.y,w2.z)
    float pxs0 = w0.x, pys0 = w0.y;
    float pxs1 = w0.w, pys1 = w1.x;
    float pxs2 = w1.z, pys2 = w1.w;
    float pxs3 = w2.y, pys3 = w2.z;
    int xi, yi;
    xi = (int)fminf(fmaxf(pxs0, 0.0f), 127.0f);
    yi = (int)fminf(fmaxf(pys0, 0.0f), 127.0f);
    m[yi * NR + xi] = 1.0f;
    xi = (int)fminf(fmaxf(pxs1, 0.0f), 127.0f);
    yi = (int)fminf(fmaxf(pys1, 0.0f), 127.0f);
    m[yi * NR + xi] = 1.0f;
    xi = (int)fminf(fmaxf(pxs2, 0.0f), 127.0f);
    yi = (int)fminf(fmaxf(pys2, 0.0f), 127.0f);
    m[yi * NR + xi] = 1.0f;
    xi = (int)fminf(fmaxf(pxs3, 0.0f), 127.0f);
    yi = (int)fminf(fmaxf(pys3, 0.0f), 127.0f);
    m[yi * NR + xi] = 1.0f;
  }
  __syncthreads();
  float4* mo = (float4*)(out + OFF_MASKS + ((size_t)b << 14));
#pragma unroll
  for (int i = 0; i < 4; ++i) mo[tid + i * 1024] = ((float4*)m)[tid + i * 1024];
}

extern "C" void kernel_launch(void* const* d_in, const int* in_sizes, int n_in,
                              void* d_out, int out_size, void* d_ws, size_t ws_size,
                              hipStream_t stream) {
  const float* roi    = (const float*)d_in[0];
  const float* focals = (const float*)d_in[1];
  const float* td     = (const float*)d_in[2];
  const float* t2     = (const float*)d_in[3];
  const float* ls     = (const float*)d_in[4];
  const float* ld     = (const float*)d_in[5];
  const float* cp     = (const float*)d_in[6];
  const float* fc     = (const float*)d_in[7];
  const float* bv     = (const float*)d_in[8];
  const float* fb     = (const float*)d_in[9];
  float* out = (float*)d_out;
  int*   Wi  = (int*)d_ws;
  float* Wf  = (float*)d_ws;

  prep_kernel<<<dim3(17), dim3(256), 0, stream>>>(
      roi, focals, td, t2, ls, ld, cp, fc, out, Wi, Wf);
  verts_kernel<<<dim3(256, NC), dim3(256), 0, stream>>>(
      bv, fb, Wi, Wf, out);
  mask_kernel<<<dim3(NB), dim3(1024), 0, stream>>>(out);
}

// Round 12
// 43.160 us; speedup vs baseline: 1.2681x; 1.0630x over previous
//
#include <hip/hip_runtime.h>
#include <math.h>

#define NB 128
#define NC 8
#define NV 16384
#define NK 64
#define NR 128

// flat output offsets (elements, f32)
#define OFF_MASKS  0
#define OFF_VP     2097152
#define OFF_THETAS 8388608
#define OFF_ALPHAS 8388736
#define OFF_ROT    8388864
#define OFF_SCALES 8389376
#define OFF_DEPTHS 8389504
#define OFF_C2D    8389632
#define OFF_TRANS  8389888
#define OFF_CLP    8390272

#define PI_F     3.14159265358979323846f
#define TWOPI_F  6.28318530717958647692f

// d_ws layout:
//   Wi[0..8]        scnt: class prefix over records
//   Wi[16..24]      cts:  class prefix over col-tiles (ceil(n_c/5) each)
//   Wi[32+r]        record -> batch id (class-sorted, r = 0..127)
//   Wf[256+r*8]     params per record: scale,qw,qy,tx,ty,tz,feff,pad
//   Wf[1280...]     Bpack (ushort): per (coltile t, kstep ks): 512 bf16
//                   elem (t*2+ks)*512 + lane*8 + j <-> B[col=lane&15][k=ks*32+(lane>>4)*8+j]

typedef short  short8 __attribute__((ext_vector_type(8)));
typedef float  f32x4  __attribute__((ext_vector_type(4)));

__device__ __forceinline__ unsigned short f2bf(float f) {
  unsigned int u = __float_as_uint(f);
  unsigned int r = (u + 0x7FFFu + ((u >> 16) & 1u)) >> 16;   // RNE
  return (unsigned short)r;
}

// ---- kernel 1: scalars + tables + bf16 B-pack (17 blocks) -------------------
__global__ __launch_bounds__(256) void prep_kernel(
    const float* __restrict__ roi, const float* __restrict__ focals,
    const float* __restrict__ td,  const float* __restrict__ t2,
    const float* __restrict__ ls,  const float* __restrict__ ld,
    const float* __restrict__ cp,  const float* __restrict__ fc,
    float* __restrict__ out, int* __restrict__ Wi, float* __restrict__ Wf) {
  int tid = threadIdx.x;
  int bx  = blockIdx.x;

  __shared__ int cls_sh[NB];
  __shared__ int rb_sh[NB];
  __shared__ int scnt_sh[NC + 1];
  __shared__ int cts_sh[NC + 1];

  int b = tid;
  int cls = 0;
  if (b < NB) {
    float pmax = cp[b * NC];
    for (int c = 1; c < NC; ++c) {
      float pv = cp[b * NC + c];
      if (pv > pmax) { pmax = pv; cls = c; }
    }
    cls_sh[b] = cls;
  }
  __syncthreads();
  if (tid <= NC) {
    int cnt = 0;
    for (int j = 0; j < NB; ++j) cnt += (cls_sh[j] < tid);
    scnt_sh[tid] = cnt;
  }
  __syncthreads();
  if (tid == 0) {
    cts_sh[0] = 0;
    for (int c = 0; c < NC; ++c) {
      int n = scnt_sh[c + 1] - scnt_sh[c];
      cts_sh[c + 1] = cts_sh[c] + (n + 4) / 5;
    }
  }
  int rank = 0;
  if (b < NB) {
    rank = scnt_sh[cls];
    for (int j = 0; j < b; ++j) rank += (cls_sh[j] == cls);
    rb_sh[rank] = b;
  }
  __syncthreads();

  if (bx == 0) {
    if (b < NB) {
      float r0 = roi[b * 4 + 0], r1 = roi[b * 4 + 1];
      float r2 = roi[b * 4 + 2], r3 = roi[b * 4 + 3];
      float dx = r2 - r0, dy = r3 - r1;
      float mx = 0.5f * (r2 + r0), my = 0.5f * (r3 + r1);
      float theta = atan2f(td[b * 2 + 1], td[b * 2 + 0]);
      float qw = cosf(0.5f * theta);
      float qy = sinf(0.5f * theta);
      float area  = dx * dy;
      float scale = expf(ls[b]);
      float depth = sqrtf(expf(ld[b]) / area);
      float cx = mx + t2[b * 2 + 0] * dx;
      float cy = my + t2[b * 2 + 1] * dy;
      float tux = cy, tuy = -cx;
      float n = sqrtf(tux * tux + tuy * tuy + 1.0f);
      float tx_ = depth * (tux / n);
      float ty_ = depth * (tuy / n);
      float tz_ = depth * (-1.0f / n);
      float alpha = -(theta - atanf(tx_ / tz_));
      float a  = alpha + PI_F;
      float rr = fmodf(a, TWOPI_F);
      if (rr < 0.0f) rr += TWOPI_F;
      float alpha_out = rr - PI_F;
      float pmax = cp[b * NC];
      for (int c = 1; c < NC; ++c) pmax = fmaxf(pmax, cp[b * NC + c]);
      float feff = 2.0f * focals[b] / (float)NR;

      out[OFF_THETAS + b]      = theta;
      out[OFF_ALPHAS + b]      = alpha_out;
      out[OFF_ROT + 4 * b + 0] = qw;
      out[OFF_ROT + 4 * b + 1] = 0.0f;
      out[OFF_ROT + 4 * b + 2] = qy;
      out[OFF_ROT + 4 * b + 3] = 0.0f;
      out[OFF_SCALES + b]      = scale;
      out[OFF_DEPTHS + b]      = depth;
      out[OFF_C2D + 2 * b + 0] = cx;
      out[OFF_C2D + 2 * b + 1] = cy;
      out[OFF_TRANS + 3 * b + 0] = tx_;
      out[OFF_TRANS + 3 * b + 1] = ty_;
      out[OFF_TRANS + 3 * b + 2] = tz_;
      out[OFF_CLP + b]         = logf(pmax);

      float* par = Wf + 256 + rank * 8;
      par[0] = scale; par[1] = qw; par[2] = qy; par[3] = tx_;
      par[4] = ty_;   par[5] = tz_; par[6] = feff; par[7] = 0.0f;
      Wi[32 + rank] = b;
    }
    if (tid <= NC) {
      Wi[tid]      = scnt_sh[tid];
      Wi[16 + tid] = cts_sh[tid];
    }
  } else {
    // blocks 1..16: pack coeffs into bf16 B-fragments
    unsigned short* BPu = (unsigned short*)(Wf + 1280);
    int total = cts_sh[NC] * 1024;      // elements
    for (int g = (bx - 1) * 256 + tid; g < total; g += 16 * 256) {
      int t   = g >> 10;
      int r10 = g & 1023;
      int ks  = r10 >> 9;
      int li  = (r10 >> 3) & 63;
      int j   = r10 & 7;
      int col = li & 15, kg = li >> 4;
      int k   = ks * 32 + kg * 8 + j;
      int c = 0;
      while (!(t >= cts_sh[c] && t < cts_sh[c + 1])) ++c;
      int local_ct = t - cts_sh[c];
      int n_c = scnt_sh[c + 1] - scnt_sh[c];
      float val = 0.0f;
      if (col < 15) {
        int lr = col / 3, comp = col - 3 * lr;
        int lrec = local_ct * 5 + lr;
        if (lrec < n_c) {
          int bb = rb_sh[scnt_sh[c] + lrec];
          val = fc[((size_t)(bb * NC + c) * NK + k) * 3 + comp];
        }
      }
      BPu[(size_t)g] = f2bf(val);
    }
  }
}

// ---- kernel 2: per-class GEMM + transform; no barriers, direct B loads ------
// grid (128, 8): x = 128-vertex super-tile, y = class. 8 waves/block.
// B slice per class is <= 8 KB and block-shared -> L1-resident; read direct.
__global__ __launch_bounds__(512) void verts_kernel(
    const float* __restrict__ basev,    // (C, V, 3)
    const float* __restrict__ basis,    // (C, V, K)
    const int*   __restrict__ Wi,
    const float* __restrict__ Wf,
    float* __restrict__ out) {
  int c   = blockIdx.y;
  int ct0 = Wi[16 + c], ct1 = Wi[16 + c + 1];
  if (ct0 >= ct1) return;
  int rec0  = Wi[c];
  int nrecs = Wi[c + 1] - rec0;

  __shared__ float s_vp[8][256];             // per-wave store staging (8 KB)

  int wave = threadIdx.x >> 6;
  int lane = threadIdx.x & 63;
  int v0   = blockIdx.x * 128 + wave * 16;
  int row  = lane & 15, kg = lane >> 4;

  // A fragments: basis[c][v0+row][k], k = ks*32 + kg*8 + j   (f32 -> bf16)
  const float* ab = basis + ((size_t)c * NV + (v0 + row)) * NK + kg * 8;
  float4 a0 = *(const float4*)(ab);
  float4 a1 = *(const float4*)(ab + 4);
  float4 a2 = *(const float4*)(ab + 32);
  float4 a3 = *(const float4*)(ab + 36);
  short8 A0, A1;
  A0[0]=f2bf(a0.x); A0[1]=f2bf(a0.y); A0[2]=f2bf(a0.z); A0[3]=f2bf(a0.w);
  A0[4]=f2bf(a1.x); A0[5]=f2bf(a1.y); A0[6]=f2bf(a1.z); A0[7]=f2bf(a1.w);
  A1[0]=f2bf(a2.x); A1[1]=f2bf(a2.y); A1[2]=f2bf(a2.z); A1[3]=f2bf(a2.w);
  A1[4]=f2bf(a3.x); A1[5]=f2bf(a3.y); A1[6]=f2bf(a3.z); A1[7]=f2bf(a3.w);

  // epilogue lane roles: q -> (record lr, component comp); rowg -> vertex group
  int q = lane & 15, rowg = lane >> 4;
  int lr = q / 3, comp = q - 3 * lr;
  bool qok = (q < 15);
  float bvx[4], bvy[4], bvz[4];
#pragma unroll
  for (int j = 0; j < 4; ++j) {
    const float* bp = basev + ((size_t)c * NV + (v0 + rowg * 4 + j)) * 3;
    bvx[j] = bp[0]; bvy[j] = bp[1]; bvz[j] = bp[2];
  }
  int sbase = lane & 48;
  int sx = sbase | (qok ? 3 * lr     : 0);
  int sy = sbase | (qok ? 3 * lr + 1 : 0);
  int sz = sbase | (qok ? 3 * lr + 2 : 0);

  // readout lane roles
  int rrec = lane / 12;            // 0..4 (lanes >= 60 idle)
  int roff = (lane % 12) * 4;      // float4 offset within the record's 48

  const float4* BP4 = (const float4*)(Wf + 1280);

  for (int t = ct0; t < ct1; ++t) {
    float4 rb0 = BP4[(size_t)(t * 2 + 0) * 64 + lane];
    float4 rb1 = BP4[(size_t)(t * 2 + 1) * 64 + lane];
    short8 B0 = *(short8*)&rb0;
    short8 B1 = *(short8*)&rb1;
    f32x4 acc = {0.0f, 0.0f, 0.0f, 0.0f};
    acc = __builtin_amdgcn_mfma_f32_16x16x32_bf16(A0, B0, acc, 0, 0, 0);
    acc = __builtin_amdgcn_mfma_f32_16x16x32_bf16(A1, B1, acc, 0, 0, 0);

    int nrec_ct = nrecs - (t - ct0) * 5;
    nrec_ct = (nrec_ct > 5) ? 5 : nrec_ct;
    bool valid = qok && (lr < nrec_ct);
    int rec = rec0 + (t - ct0) * 5 + (valid ? lr : 0);
    float4 P0 = *(const float4*)(Wf + 256 + rec * 8);
    float4 P1 = *(const float4*)(Wf + 256 + rec * 8 + 4);
    float scale = P0.x, qw = P0.y, qy = P0.z, tx = P0.w;
    float ty = P1.x, tz = P1.y, feff = P1.z;

#pragma unroll
    for (int j = 0; j < 4; ++j) {
      float dx_ = __shfl(acc[j], sx);
      float dy_ = __shfl(acc[j], sy);
      float dz_ = __shfl(acc[j], sz);

      float vx = (bvx[j] + dx_) * scale;
      float vy = (bvy[j] + dy_) * scale;
      float vz = (bvz[j] + dz_) * scale;
      float t2x = 2.0f * qy * vz;
      float t2z = -2.0f * qy * vx;
      float rx = vx + qw * t2x + qy * t2z;
      float ry = vy;
      float rz = vz + qw * t2z - qy * t2x;
      float wx = rx + tx, wy = ry + ty, wz = rz + tz;

      float zv = wz;
      float zsafe = (zv > -1e-4f) ? -1e-4f : zv;
      float inv = feff / (-zsafe);
      float px = (wx * inv * 0.5f + 0.5f) * (float)NR;
      float py = (wy * inv * 0.5f + 0.5f) * (float)NR;

      float ov = (comp == 0) ? px : ((comp == 1) ? py : -zv);
      if (qok) s_vp[wave][lr * 48 + (rowg * 4 + j) * 3 + comp] = ov;
    }
    // in-order per-wave DS: reads below see the writes above (no barrier)
    if (lane < 60 && rrec < nrec_ct) {
      float4 val = *(float4*)&s_vp[wave][rrec * 48 + roff];
      int rrec_g = rec0 + (t - ct0) * 5 + rrec;
      int bb = Wi[32 + rrec_g];
      *(float4*)&out[OFF_VP + ((size_t)bb * NV + v0) * 3 + roff] = val;
    }
  }
}

// ---- kernel 3: batch-major mask build, 1024 threads, float4-coalesced -------
__global__ __launch_bounds__(1024) void mask_kernel(float* __restrict__ out) {
  int b   = blockIdx.x;
  int tid = threadIdx.x;
  __shared__ float m[NR * NR];   // 64 KB
  float4 z4; z4.x = 0.0f; z4.y = 0.0f; z4.z = 0.0f; z4.w = 0.0f;
#pragma unroll
  for (int i = 0; i < 4; ++i) ((float4*)m)[tid + i * 1024] = z4;
  __syncthreads();
  const float4* vb4 = (const float4*)(out + OFF_VP + (size_t)b * NV * 3);
#pragma unroll
  for (int i = 0; i < 4; ++i) {
    int g = tid + i * 1024;              // vertex group of 4 (floats 12g..12g+11)
    float4 w0 = vb4[3 * g + 0];
    float4 w1 = vb4[3 * g + 1];
    float4 w2 = vb4[3 * g + 2];
    // pairs: (w0.x,w0.y) (w0.w,w1.x) (w1.z,w1.w) (w2.y,w2.z)
    float pxs0 = w0.x, pys0 = w0.y;
    float pxs1 = w0.w, pys1 = w1.x;
    float pxs2 = w1.z, pys2 = w1.w;
    float pxs3 = w2.y, pys3 = w2.z;
    int xi, yi;
    xi = (int)fminf(fmaxf(pxs0, 0.0f), 127.0f);
    yi = (int)fminf(fmaxf(pys0, 0.0f), 127.0f);
    m[yi * NR + xi] = 1.0f;
    xi = (int)fminf(fmaxf(pxs1, 0.0f), 127.0f);
    yi = (int)fminf(fmaxf(pys1, 0.0f), 127.0f);
    m[yi * NR + xi] = 1.0f;
    xi = (int)fminf(fmaxf(pxs2, 0.0f), 127.0f);
    yi = (int)fminf(fmaxf(pys2, 0.0f), 127.0f);
    m[yi * NR + xi] = 1.0f;
    xi = (int)fminf(fmaxf(pxs3, 0.0f), 127.0f);
    yi = (int)fminf(fmaxf(pys3, 0.0f), 127.0f);
    m[yi * NR + xi] = 1.0f;
  }
  __syncthreads();
  float4* mo = (float4*)(out + OFF_MASKS + ((size_t)b << 14));
#pragma unroll
  for (int i = 0; i < 4; ++i) mo[tid + i * 1024] = ((float4*)m)[tid + i * 1024];
}

extern "C" void kernel_launch(void* const* d_in, const int* in_sizes, int n_in,
                              void* d_out, int out_size, void* d_ws, size_t ws_size,
                              hipStream_t stream) {
  const float* roi    = (const float*)d_in[0];
  const float* focals = (const float*)d_in[1];
  const float* td     = (const float*)d_in[2];
  const float* t2     = (const float*)d_in[3];
  const float* ls     = (const float*)d_in[4];
  const float* ld     = (const float*)d_in[5];
  const float* cp     = (const float*)d_in[6];
  const float* fc     = (const float*)d_in[7];
  const float* bv     = (const float*)d_in[8];
  const float* fb     = (const float*)d_in[9];
  float* out = (float*)d_out;
  int*   Wi  = (int*)d_ws;
  float* Wf  = (float*)d_ws;

  prep_kernel<<<dim3(17), dim3(256), 0, stream>>>(
      roi, focals, td, t2, ls, ld, cp, fc, out, Wi, Wf);
  verts_kernel<<<dim3(NV / 128, NC), dim3(512), 0, stream>>>(
      bv, fb, Wi, Wf, out);
  mask_kernel<<<dim3(NB), dim3(1024), 0, stream>>>(out);
}

// Round 13
// 42.033 us; speedup vs baseline: 1.3021x; 1.0268x over previous
//
#include <hip/hip_runtime.h>
#include <math.h>

#define NB 128
#define NC 8
#define NV 16384
#define NK 64
#define NR 128

// flat output offsets (elements, f32)
#define OFF_MASKS  0
#define OFF_VP     2097152
#define OFF_THETAS 8388608
#define OFF_ALPHAS 8388736
#define OFF_ROT    8388864
#define OFF_SCALES 8389376
#define OFF_DEPTHS 8389504
#define OFF_C2D    8389632
#define OFF_TRANS  8389888
#define OFF_CLP    8390272

#define PI_F     3.14159265358979323846f
#define TWOPI_F  6.28318530717958647692f

// d_ws layout:
//   Wi[0..8]        scnt: class prefix over records
//   Wi[16..24]      cts:  class prefix over col-tiles (ceil(n_c/5) each)
//   Wi[32+r]        record -> batch id (class-sorted, r = 0..127)
//   Wf[256+r*8]     params per record: scale, c2=1-2qy^2, s2=2qw*qy, tx,ty,tz,feff,pad
//   Wf[1280...]     Bpack (ushort): per (coltile t, kstep ks): 512 bf16
//                   elem (t*2+ks)*512 + lane*8 + j <-> B[col=lane&15][k=ks*32+(lane>>4)*8+j]

typedef short  short8 __attribute__((ext_vector_type(8)));
typedef float  f32x4  __attribute__((ext_vector_type(4)));

__device__ __forceinline__ unsigned short f2bf(float f) {
  unsigned int u = __float_as_uint(f);
  unsigned int r = (u + 0x7FFFu + ((u >> 16) & 1u)) >> 16;   // RNE
  return (unsigned short)r;
}

// ---- kernel 1: scalars + tables + bf16 B-pack (17 blocks) -------------------
__global__ __launch_bounds__(256) void prep_kernel(
    const float* __restrict__ roi, const float* __restrict__ focals,
    const float* __restrict__ td,  const float* __restrict__ t2,
    const float* __restrict__ ls,  const float* __restrict__ ld,
    const float* __restrict__ cp,  const float* __restrict__ fc,
    float* __restrict__ out, int* __restrict__ Wi, float* __restrict__ Wf) {
  int tid = threadIdx.x;
  int bx  = blockIdx.x;

  __shared__ int cls_sh[NB];
  __shared__ int rb_sh[NB];
  __shared__ int scnt_sh[NC + 1];
  __shared__ int cts_sh[NC + 1];

  int b = tid;
  int cls = 0;
  if (b < NB) {
    float pmax = cp[b * NC];
    for (int c = 1; c < NC; ++c) {
      float pv = cp[b * NC + c];
      if (pv > pmax) { pmax = pv; cls = c; }
    }
    cls_sh[b] = cls;
  }
  __syncthreads();
  if (tid <= NC) {
    int cnt = 0;
    for (int j = 0; j < NB; ++j) cnt += (cls_sh[j] < tid);
    scnt_sh[tid] = cnt;
  }
  __syncthreads();
  if (tid == 0) {
    cts_sh[0] = 0;
    for (int c = 0; c < NC; ++c) {
      int n = scnt_sh[c + 1] - scnt_sh[c];
      cts_sh[c + 1] = cts_sh[c] + (n + 4) / 5;
    }
  }
  int rank = 0;
  if (b < NB) {
    rank = scnt_sh[cls];
    for (int j = 0; j < b; ++j) rank += (cls_sh[j] == cls);
    rb_sh[rank] = b;
  }
  __syncthreads();

  if (bx == 0) {
    if (b < NB) {
      float r0 = roi[b * 4 + 0], r1 = roi[b * 4 + 1];
      float r2 = roi[b * 4 + 2], r3 = roi[b * 4 + 3];
      float dx = r2 - r0, dy = r3 - r1;
      float mx = 0.5f * (r2 + r0), my = 0.5f * (r3 + r1);
      float theta = atan2f(td[b * 2 + 1], td[b * 2 + 0]);
      float qw = cosf(0.5f * theta);
      float qy = sinf(0.5f * theta);
      float area  = dx * dy;
      float scale = expf(ls[b]);
      float depth = sqrtf(expf(ld[b]) / area);
      float cx = mx + t2[b * 2 + 0] * dx;
      float cy = my + t2[b * 2 + 1] * dy;
      float tux = cy, tuy = -cx;
      float n = sqrtf(tux * tux + tuy * tuy + 1.0f);
      float tx_ = depth * (tux / n);
      float ty_ = depth * (tuy / n);
      float tz_ = depth * (-1.0f / n);
      float alpha = -(theta - atanf(tx_ / tz_));
      float a  = alpha + PI_F;
      float rr = fmodf(a, TWOPI_F);
      if (rr < 0.0f) rr += TWOPI_F;
      float alpha_out = rr - PI_F;
      float pmax = cp[b * NC];
      for (int c = 1; c < NC; ++c) pmax = fmaxf(pmax, cp[b * NC + c]);
      float feff = 2.0f * focals[b] / (float)NR;

      out[OFF_THETAS + b]      = theta;
      out[OFF_ALPHAS + b]      = alpha_out;
      out[OFF_ROT + 4 * b + 0] = qw;
      out[OFF_ROT + 4 * b + 1] = 0.0f;
      out[OFF_ROT + 4 * b + 2] = qy;
      out[OFF_ROT + 4 * b + 3] = 0.0f;
      out[OFF_SCALES + b]      = scale;
      out[OFF_DEPTHS + b]      = depth;
      out[OFF_C2D + 2 * b + 0] = cx;
      out[OFF_C2D + 2 * b + 1] = cy;
      out[OFF_TRANS + 3 * b + 0] = tx_;
      out[OFF_TRANS + 3 * b + 1] = ty_;
      out[OFF_TRANS + 3 * b + 2] = tz_;
      out[OFF_CLP + b]         = logf(pmax);

      float* par = Wf + 256 + rank * 8;
      par[0] = scale;
      par[1] = 1.0f - 2.0f * qy * qy;   // c2
      par[2] = 2.0f * qw * qy;          // s2
      par[3] = tx_;
      par[4] = ty_;   par[5] = tz_; par[6] = feff; par[7] = 0.0f;
      Wi[32 + rank] = b;
    }
    if (tid <= NC) {
      Wi[tid]      = scnt_sh[tid];
      Wi[16 + tid] = cts_sh[tid];
    }
  } else {
    // blocks 1..16: pack coeffs into bf16 B-fragments
    unsigned short* BPu = (unsigned short*)(Wf + 1280);
    int total = cts_sh[NC] * 1024;      // elements
    for (int g = (bx - 1) * 256 + tid; g < total; g += 16 * 256) {
      int t   = g >> 10;
      int r10 = g & 1023;
      int ks  = r10 >> 9;
      int li  = (r10 >> 3) & 63;
      int j   = r10 & 7;
      int col = li & 15, kg = li >> 4;
      int k   = ks * 32 + kg * 8 + j;
      int c = 0;
      while (!(t >= cts_sh[c] && t < cts_sh[c + 1])) ++c;
      int local_ct = t - cts_sh[c];
      int n_c = scnt_sh[c + 1] - scnt_sh[c];
      float val = 0.0f;
      if (col < 15) {
        int lr = col / 3, comp = col - 3 * lr;
        int lrec = local_ct * 5 + lr;
        if (lrec < n_c) {
          int bb = rb_sh[scnt_sh[c] + lrec];
          val = fc[((size_t)(bb * NC + c) * NK + k) * 3 + comp];
        }
      }
      BPu[(size_t)g] = f2bf(val);
    }
  }
}

// ---- kernel 2: per-class GEMM + comp-specialized epilogue -------------------
// grid (128, 8): x = 128-vertex super-tile, y = class. 8 waves/block.
// Each lane transforms ONLY its own component; cross-lane traffic is
// 2 bpermutes/j (partner v, then inv) instead of 3 gathers + full redundant
// transform in every lane.
__global__ __launch_bounds__(512) void verts_kernel(
    const float* __restrict__ basev,    // (C, V, 3)
    const float* __restrict__ basis,    // (C, V, K)
    const int*   __restrict__ Wi,
    const float* __restrict__ Wf,
    float* __restrict__ out) {
  int c   = blockIdx.y;
  int ct0 = Wi[16 + c], ct1 = Wi[16 + c + 1];
  if (ct0 >= ct1) return;
  int rec0  = Wi[c];
  int nrecs = Wi[c + 1] - rec0;

  __shared__ float s_vp[8][256];             // per-wave store staging (8 KB)

  int wave = threadIdx.x >> 6;
  int lane = threadIdx.x & 63;
  int v0   = blockIdx.x * 128 + wave * 16;
  int row  = lane & 15, kg = lane >> 4;

  // A fragments: basis[c][v0+row][k], k = ks*32 + kg*8 + j   (f32 -> bf16)
  const float* ab = basis + ((size_t)c * NV + (v0 + row)) * NK + kg * 8;
  float4 a0 = *(const float4*)(ab);
  float4 a1 = *(const float4*)(ab + 4);
  float4 a2 = *(const float4*)(ab + 32);
  float4 a3 = *(const float4*)(ab + 36);
  short8 A0, A1;
  A0[0]=f2bf(a0.x); A0[1]=f2bf(a0.y); A0[2]=f2bf(a0.z); A0[3]=f2bf(a0.w);
  A0[4]=f2bf(a1.x); A0[5]=f2bf(a1.y); A0[6]=f2bf(a1.z); A0[7]=f2bf(a1.w);
  A1[0]=f2bf(a2.x); A1[1]=f2bf(a2.y); A1[2]=f2bf(a2.z); A1[3]=f2bf(a2.w);
  A1[4]=f2bf(a3.x); A1[5]=f2bf(a3.y); A1[6]=f2bf(a3.z); A1[7]=f2bf(a3.w);

  // epilogue lane roles: q -> (record lr, component comp); rowg -> vertex group
  int q = lane & 15, rowg = lane >> 4;
  int lr = q / 3, comp = q - 3 * lr;
  bool qok = (q < 15);
  // per-lane base-vertex component (own comp only)
  float bvo[4];
#pragma unroll
  for (int j = 0; j < 4; ++j)
    bvo[j] = basev[((size_t)c * NV + (v0 + rowg * 4 + j)) * 3 + (qok ? comp : 0)];
  int sbase = lane & 48;
  int sxi = sbase | (qok ? 3 * lr     : 0);   // x-lane of my record
  int szi = sbase | (qok ? 3 * lr + 2 : 0);   // z-lane of my record
  // round-1 partner: x pulls vz, z pulls vx, y pulls self
  int pull1 = (comp == 0) ? szi : ((comp == 2) ? sxi : lane);
  // round-2: x,y pull inv from z-lane; z pulls self
  int pull2 = (comp == 2) ? lane : szi;

  // readout lane roles
  int rrec = lane / 12;            // 0..4 (lanes >= 60 idle)
  int roff = (lane % 12) * 4;      // float4 offset within the record's 48

  const float4* BP4 = (const float4*)(Wf + 1280);

  for (int t = ct0; t < ct1; ++t) {
    float4 rb0 = BP4[(size_t)(t * 2 + 0) * 64 + lane];
    float4 rb1 = BP4[(size_t)(t * 2 + 1) * 64 + lane];
    short8 B0 = *(short8*)&rb0;
    short8 B1 = *(short8*)&rb1;
    f32x4 acc = {0.0f, 0.0f, 0.0f, 0.0f};
    acc = __builtin_amdgcn_mfma_f32_16x16x32_bf16(A0, B0, acc, 0, 0, 0);
    acc = __builtin_amdgcn_mfma_f32_16x16x32_bf16(A1, B1, acc, 0, 0, 0);

    int nrec_ct = nrecs - (t - ct0) * 5;
    nrec_ct = (nrec_ct > 5) ? 5 : nrec_ct;
    bool valid = qok && (lr < nrec_ct);
    int rec = rec0 + (t - ct0) * 5 + (valid ? lr : 0);
    float4 P0 = *(const float4*)(Wf + 256 + rec * 8);
    float4 P1 = *(const float4*)(Wf + 256 + rec * 8 + 4);
    float scale = P0.x, c2 = P0.y, s2 = P0.z, tx = P0.w;
    float ty = P1.x, tz = P1.y, feff = P1.z;
    // per-lane translation
    float tro = (comp == 0) ? tx : ((comp == 1) ? ty : tz);

#pragma unroll
    for (int j = 0; j < 4; ++j) {
      float vown = (bvo[j] + acc[j]) * scale;
      float vpart = __shfl(vown, pull1);
      // w = own world component:
      //   x: vx*c2 + s2*vz + tx ;  y: vy + ty ;  z: vz*c2 - s2*vx + tz
      float rot = (comp == 1) ? vown
                : fmaf(vown, c2, (comp == 0) ? s2 * vpart : -s2 * vpart);
      float w = rot + tro;
      // z-lane computes inv; others compute garbage then overwrite via pull
      float zsafe = (w > -1e-4f) ? -1e-4f : w;
      float invz  = feff / (-zsafe);
      float invp  = __shfl(invz, pull2);
      float ov = (comp == 2) ? -w : (w * invp * 0.5f + 0.5f) * (float)NR;
      if (qok) s_vp[wave][lr * 48 + (rowg * 4 + j) * 3 + comp] = ov;
    }
    // in-order per-wave DS: reads below see the writes above (no barrier)
    if (lane < 60 && rrec < nrec_ct) {
      float4 val = *(float4*)&s_vp[wave][rrec * 48 + roff];
      int rrec_g = rec0 + (t - ct0) * 5 + rrec;
      int bb = Wi[32 + rrec_g];
      *(float4*)&out[OFF_VP + ((size_t)bb * NV + v0) * 3 + roff] = val;
    }
  }
}

// ---- kernel 3: batch-major mask build, 1024 threads, float4-coalesced -------
__global__ __launch_bounds__(1024) void mask_kernel(float* __restrict__ out) {
  int b   = blockIdx.x;
  int tid = threadIdx.x;
  __shared__ float m[NR * NR];   // 64 KB
  float4 z4; z4.x = 0.0f; z4.y = 0.0f; z4.z = 0.0f; z4.w = 0.0f;
#pragma unroll
  for (int i = 0; i < 4; ++i) ((float4*)m)[tid + i * 1024] = z4;
  __syncthreads();
  const float4* vb4 = (const float4*)(out + OFF_VP + (size_t)b * NV * 3);
#pragma unroll
  for (int i = 0; i < 4; ++i) {
    int g = tid + i * 1024;              // vertex group of 4 (floats 12g..12g+11)
    float4 w0 = vb4[3 * g + 0];
    float4 w1 = vb4[3 * g + 1];
    float4 w2 = vb4[3 * g + 2];
    // pairs: (w0.x,w0.y) (w0.w,w1.x) (w1.z,w1.w) (w2.y,w2.z)
    float pxs0 = w0.x, pys0 = w0.y;
    float pxs1 = w0.w, pys1 = w1.x;
    float pxs2 = w1.z, pys2 = w1.w;
    float pxs3 = w2.y, pys3 = w2.z;
    int xi, yi;
    xi = (int)fminf(fmaxf(pxs0, 0.0f), 127.0f);
    yi = (int)fminf(fmaxf(pys0, 0.0f), 127.0f);
    m[yi * NR + xi] = 1.0f;
    xi = (int)fminf(fmaxf(pxs1, 0.0f), 127.0f);
    yi = (int)fminf(fmaxf(pys1, 0.0f), 127.0f);
    m[yi * NR + xi] = 1.0f;
    xi = (int)fminf(fmaxf(pxs2, 0.0f), 127.0f);
    yi = (int)fminf(fmaxf(pys2, 0.0f), 127.0f);
    m[yi * NR + xi] = 1.0f;
    xi = (int)fminf(fmaxf(pxs3, 0.0f), 127.0f);
    yi = (int)fminf(fmaxf(pys3, 0.0f), 127.0f);
    m[yi * NR + xi] = 1.0f;
  }
  __syncthreads();
  float4* mo = (float4*)(out + OFF_MASKS + ((size_t)b << 14));
#pragma unroll
  for (int i = 0; i < 4; ++i) mo[tid + i * 1024] = ((float4*)m)[tid + i * 1024];
}

extern "C" void kernel_launch(void* const* d_in, const int* in_sizes, int n_in,
                              void* d_out, int out_size, void* d_ws, size_t ws_size,
                              hipStream_t stream) {
  const float* roi    = (const float*)d_in[0];
  const float* focals = (const float*)d_in[1];
  const float* td     = (const float*)d_in[2];
  const float* t2     = (const float*)d_in[3];
  const float* ls     = (const float*)d_in[4];
  const float* ld     = (const float*)d_in[5];
  const float* cp     = (const float*)d_in[6];
  const float* fc     = (const float*)d_in[7];
  const float* bv     = (const float*)d_in[8];
  const float* fb     = (const float*)d_in[9];
  float* out = (float*)d_out;
  int*   Wi  = (int*)d_ws;
  float* Wf  = (float*)d_ws;

  prep_kernel<<<dim3(17), dim3(256), 0, stream>>>(
      roi, focals, td, t2, ls, ld, cp, fc, out, Wi, Wf);
  verts_kernel<<<dim3(NV / 128, NC), dim3(512), 0, stream>>>(
      bv, fb, Wi, Wf, out);
  mask_kernel<<<dim3(NB), dim3(1024), 0, stream>>>(out);
}

// Round 14
// 41.050 us; speedup vs baseline: 1.3333x; 1.0240x over previous
//
#include <hip/hip_runtime.h>
#include <math.h>

#define NB 128
#define NC 8
#define NV 16384
#define NK 64
#define NR 128

// flat output offsets (elements, f32)
#define OFF_MASKS  0
#define OFF_VP     2097152
#define OFF_THETAS 8388608
#define OFF_ALPHAS 8388736
#define OFF_ROT    8388864
#define OFF_SCALES 8389376
#define OFF_DEPTHS 8389504
#define OFF_C2D    8389632
#define OFF_TRANS  8389888
#define OFF_CLP    8390272

#define PI_F     3.14159265358979323846f
#define TWOPI_F  6.28318530717958647692f

// d_ws layout:
//   Wi[0..8]        scnt: class prefix over records
//   Wi[16..24]      cts:  class prefix over col-tiles (ceil(n_c/5) each)
//   Wi[32+r]        record -> batch id (class-sorted, r = 0..127)
//   Wf[256+r*8]     params per record: scale, c2=1-2qy^2, s2=2qw*qy, tx,ty,tz,feff,pad
//   Wf[1280...]     Bpack (ushort): per (coltile t, kstep ks): 512 bf16
//                   elem (t*2+ks)*512 + lane*8 + j <-> B[col=lane&15][k=ks*32+(lane>>4)*8+j]

typedef short  short8 __attribute__((ext_vector_type(8)));
typedef float  f32x4  __attribute__((ext_vector_type(4)));

__device__ __forceinline__ unsigned short f2bf(float f) {
  unsigned int u = __float_as_uint(f);
  unsigned int r = (u + 0x7FFFu + ((u >> 16) & 1u)) >> 16;   // RNE
  return (unsigned short)r;
}

// ---- kernel 1: mask zero-fill (all 2048 blocks) + scalars + B-pack ----------
__global__ __launch_bounds__(256) void prep_kernel(
    const float* __restrict__ roi, const float* __restrict__ focals,
    const float* __restrict__ td,  const float* __restrict__ t2,
    const float* __restrict__ ls,  const float* __restrict__ ld,
    const float* __restrict__ cp,  const float* __restrict__ fc,
    float* __restrict__ out, int* __restrict__ Wi, float* __restrict__ Wf) {
  int tid = threadIdx.x;
  int bx  = blockIdx.x;
  {
    // zero the whole mask region: 2048 blocks * 256 threads * 1 float4
    int i = bx * 256 + tid;
    float4 z; z.x = 0.0f; z.y = 0.0f; z.z = 0.0f; z.w = 0.0f;
    ((float4*)(out + OFF_MASKS))[i] = z;
  }
  if (bx > 16) return;

  __shared__ int cls_sh[NB];
  __shared__ int rb_sh[NB];
  __shared__ int scnt_sh[NC + 1];
  __shared__ int cts_sh[NC + 1];

  int b = tid;
  int cls = 0;
  if (b < NB) {
    float pmax = cp[b * NC];
    for (int c = 1; c < NC; ++c) {
      float pv = cp[b * NC + c];
      if (pv > pmax) { pmax = pv; cls = c; }
    }
    cls_sh[b] = cls;
  }
  __syncthreads();
  if (tid <= NC) {
    int cnt = 0;
    for (int j = 0; j < NB; ++j) cnt += (cls_sh[j] < tid);
    scnt_sh[tid] = cnt;
  }
  __syncthreads();
  if (tid == 0) {
    cts_sh[0] = 0;
    for (int c = 0; c < NC; ++c) {
      int n = scnt_sh[c + 1] - scnt_sh[c];
      cts_sh[c + 1] = cts_sh[c] + (n + 4) / 5;
    }
  }
  int rank = 0;
  if (b < NB) {
    rank = scnt_sh[cls];
    for (int j = 0; j < b; ++j) rank += (cls_sh[j] == cls);
    rb_sh[rank] = b;
  }
  __syncthreads();

  if (bx == 0) {
    if (b < NB) {
      float r0 = roi[b * 4 + 0], r1 = roi[b * 4 + 1];
      float r2 = roi[b * 4 + 2], r3 = roi[b * 4 + 3];
      float dx = r2 - r0, dy = r3 - r1;
      float mx = 0.5f * (r2 + r0), my = 0.5f * (r3 + r1);
      float theta = atan2f(td[b * 2 + 1], td[b * 2 + 0]);
      float qw = cosf(0.5f * theta);
      float qy = sinf(0.5f * theta);
      float area  = dx * dy;
      float scale = expf(ls[b]);
      float depth = sqrtf(expf(ld[b]) / area);
      float cx = mx + t2[b * 2 + 0] * dx;
      float cy = my + t2[b * 2 + 1] * dy;
      float tux = cy, tuy = -cx;
      float n = sqrtf(tux * tux + tuy * tuy + 1.0f);
      float tx_ = depth * (tux / n);
      float ty_ = depth * (tuy / n);
      float tz_ = depth * (-1.0f / n);
      float alpha = -(theta - atanf(tx_ / tz_));
      float a  = alpha + PI_F;
      float rr = fmodf(a, TWOPI_F);
      if (rr < 0.0f) rr += TWOPI_F;
      float alpha_out = rr - PI_F;
      float pmax = cp[b * NC];
      for (int c = 1; c < NC; ++c) pmax = fmaxf(pmax, cp[b * NC + c]);
      float feff = 2.0f * focals[b] / (float)NR;

      out[OFF_THETAS + b]      = theta;
      out[OFF_ALPHAS + b]      = alpha_out;
      out[OFF_ROT + 4 * b + 0] = qw;
      out[OFF_ROT + 4 * b + 1] = 0.0f;
      out[OFF_ROT + 4 * b + 2] = qy;
      out[OFF_ROT + 4 * b + 3] = 0.0f;
      out[OFF_SCALES + b]      = scale;
      out[OFF_DEPTHS + b]      = depth;
      out[OFF_C2D + 2 * b + 0] = cx;
      out[OFF_C2D + 2 * b + 1] = cy;
      out[OFF_TRANS + 3 * b + 0] = tx_;
      out[OFF_TRANS + 3 * b + 1] = ty_;
      out[OFF_TRANS + 3 * b + 2] = tz_;
      out[OFF_CLP + b]         = logf(pmax);

      float* par = Wf + 256 + rank * 8;
      par[0] = scale;
      par[1] = 1.0f - 2.0f * qy * qy;   // c2
      par[2] = 2.0f * qw * qy;          // s2
      par[3] = tx_;
      par[4] = ty_;   par[5] = tz_; par[6] = feff; par[7] = 0.0f;
      Wi[32 + rank] = b;
    }
    if (tid <= NC) {
      Wi[tid]      = scnt_sh[tid];
      Wi[16 + tid] = cts_sh[tid];
    }
  } else {
    // blocks 1..16: pack coeffs into bf16 B-fragments
    unsigned short* BPu = (unsigned short*)(Wf + 1280);
    int total = cts_sh[NC] * 1024;      // elements
    for (int g = (bx - 1) * 256 + tid; g < total; g += 16 * 256) {
      int t   = g >> 10;
      int r10 = g & 1023;
      int ks  = r10 >> 9;
      int li  = (r10 >> 3) & 63;
      int j   = r10 & 7;
      int col = li & 15, kg = li >> 4;
      int k   = ks * 32 + kg * 8 + j;
      int c = 0;
      while (!(t >= cts_sh[c] && t < cts_sh[c + 1])) ++c;
      int local_ct = t - cts_sh[c];
      int n_c = scnt_sh[c + 1] - scnt_sh[c];
      float val = 0.0f;
      if (col < 15) {
        int lr = col / 3, comp = col - 3 * lr;
        int lrec = local_ct * 5 + lr;
        if (lrec < n_c) {
          int bb = rb_sh[scnt_sh[c] + lrec];
          val = fc[((size_t)(bb * NC + c) * NK + k) * 3 + comp];
        }
      }
      BPu[(size_t)g] = f2bf(val);
    }
  }
}

// ---- kernel 2: per-class GEMM + comp-specialized epilogue + fused scatter ---
// grid (128, 8): x = 128-vertex super-tile, y = class. 8 waves/block.
// x-lanes additionally pull py from their record's y-lane and scatter 1.0
// into the batch mask (no separate mask pass; vp never re-read).
__global__ __launch_bounds__(512) void verts_kernel(
    const float* __restrict__ basev,    // (C, V, 3)
    const float* __restrict__ basis,    // (C, V, K)
    const int*   __restrict__ Wi,
    const float* __restrict__ Wf,
    float* __restrict__ out) {
  int c   = blockIdx.y;
  int ct0 = Wi[16 + c], ct1 = Wi[16 + c + 1];
  if (ct0 >= ct1) return;
  int rec0  = Wi[c];
  int nrecs = Wi[c + 1] - rec0;

  __shared__ float s_vp[8][256];             // per-wave store staging (8 KB)

  int wave = threadIdx.x >> 6;
  int lane = threadIdx.x & 63;
  int v0   = blockIdx.x * 128 + wave * 16;
  int row  = lane & 15, kg = lane >> 4;

  // A fragments: basis[c][v0+row][k], k = ks*32 + kg*8 + j   (f32 -> bf16)
  const float* ab = basis + ((size_t)c * NV + (v0 + row)) * NK + kg * 8;
  float4 a0 = *(const float4*)(ab);
  float4 a1 = *(const float4*)(ab + 4);
  float4 a2 = *(const float4*)(ab + 32);
  float4 a3 = *(const float4*)(ab + 36);
  short8 A0, A1;
  A0[0]=f2bf(a0.x); A0[1]=f2bf(a0.y); A0[2]=f2bf(a0.z); A0[3]=f2bf(a0.w);
  A0[4]=f2bf(a1.x); A0[5]=f2bf(a1.y); A0[6]=f2bf(a1.z); A0[7]=f2bf(a1.w);
  A1[0]=f2bf(a2.x); A1[1]=f2bf(a2.y); A1[2]=f2bf(a2.z); A1[3]=f2bf(a2.w);
  A1[4]=f2bf(a3.x); A1[5]=f2bf(a3.y); A1[6]=f2bf(a3.z); A1[7]=f2bf(a3.w);

  // epilogue lane roles: q -> (record lr, component comp); rowg -> vertex group
  int q = lane & 15, rowg = lane >> 4;
  int lr = q / 3, comp = q - 3 * lr;
  bool qok = (q < 15);
  // per-lane base-vertex component (own comp only)
  float bvo[4];
#pragma unroll
  for (int j = 0; j < 4; ++j)
    bvo[j] = basev[((size_t)c * NV + (v0 + rowg * 4 + j)) * 3 + (qok ? comp : 0)];
  int sbase = lane & 48;
  int sxi = sbase | (qok ? 3 * lr     : 0);   // x-lane of my record
  int syi = sbase | (qok ? 3 * lr + 1 : 0);   // y-lane of my record
  int szi = sbase | (qok ? 3 * lr + 2 : 0);   // z-lane of my record
  // round-1 partner: x pulls vz, z pulls vx, y pulls self
  int pull1 = (comp == 0) ? szi : ((comp == 2) ? sxi : lane);
  // round-2: x,y pull inv from z-lane; z pulls self
  int pull2 = (comp == 2) ? lane : szi;
  // round-3 (mask): x pulls py from y-lane; others pull self (unused)
  int pull3 = (comp == 0) ? syi : lane;

  // readout lane roles
  int rrec = lane / 12;            // 0..4 (lanes >= 60 idle)
  int roff = (lane % 12) * 4;      // float4 offset within the record's 48

  const float4* BP4 = (const float4*)(Wf + 1280);

  for (int t = ct0; t < ct1; ++t) {
    float4 rb0 = BP4[(size_t)(t * 2 + 0) * 64 + lane];
    float4 rb1 = BP4[(size_t)(t * 2 + 1) * 64 + lane];
    short8 B0 = *(short8*)&rb0;
    short8 B1 = *(short8*)&rb1;
    f32x4 acc = {0.0f, 0.0f, 0.0f, 0.0f};
    acc = __builtin_amdgcn_mfma_f32_16x16x32_bf16(A0, B0, acc, 0, 0, 0);
    acc = __builtin_amdgcn_mfma_f32_16x16x32_bf16(A1, B1, acc, 0, 0, 0);

    int nrec_ct = nrecs - (t - ct0) * 5;
    nrec_ct = (nrec_ct > 5) ? 5 : nrec_ct;
    bool valid = qok && (lr < nrec_ct);
    int rec = rec0 + (t - ct0) * 5 + (valid ? lr : 0);
    int bb  = Wi[32 + rec];
    float4 P0 = *(const float4*)(Wf + 256 + rec * 8);
    float4 P1 = *(const float4*)(Wf + 256 + rec * 8 + 4);
    float scale = P0.x, c2 = P0.y, s2 = P0.z, tx = P0.w;
    float ty = P1.x, tz = P1.y, feff = P1.z;
    // per-lane translation
    float tro = (comp == 0) ? tx : ((comp == 1) ? ty : tz);

#pragma unroll
    for (int j = 0; j < 4; ++j) {
      float vown = (bvo[j] + acc[j]) * scale;
      float vpart = __shfl(vown, pull1);
      // w = own world component:
      //   x: vx*c2 + s2*vz + tx ;  y: vy + ty ;  z: vz*c2 - s2*vx + tz
      float rot = (comp == 1) ? vown
                : fmaf(vown, c2, (comp == 0) ? s2 * vpart : -s2 * vpart);
      float w = rot + tro;
      // z-lane computes inv; others pull it
      float zsafe = (w > -1e-4f) ? -1e-4f : w;
      float invz  = feff / (-zsafe);
      float invp  = __shfl(invz, pull2);
      float ov = (comp == 2) ? -w : (w * invp * 0.5f + 0.5f) * (float)NR;
      if (qok) s_vp[wave][lr * 48 + (rowg * 4 + j) * 3 + comp] = ov;
      // fused mask scatter: x-lane has px=ov, pulls py from y-lane
      float pyv = __shfl(ov, pull3);
      if (valid && comp == 0) {
        int xi = (int)fminf(fmaxf(ov,  0.0f), 127.0f);
        int yi = (int)fminf(fmaxf(pyv, 0.0f), 127.0f);
        out[OFF_MASKS + (bb << 14) + yi * NR + xi] = 1.0f;
      }
    }
    // in-order per-wave DS: reads below see the writes above (no barrier)
    if (lane < 60 && rrec < nrec_ct) {
      float4 val = *(float4*)&s_vp[wave][rrec * 48 + roff];
      int rrec_g = rec0 + (t - ct0) * 5 + rrec;
      int bb2 = Wi[32 + rrec_g];
      *(float4*)&out[OFF_VP + ((size_t)bb2 * NV + v0) * 3 + roff] = val;
    }
  }
}

extern "C" void kernel_launch(void* const* d_in, const int* in_sizes, int n_in,
                              void* d_out, int out_size, void* d_ws, size_t ws_size,
                              hipStream_t stream) {
  const float* roi    = (const float*)d_in[0];
  const float* focals = (const float*)d_in[1];
  const float* td     = (const float*)d_in[2];
  const float* t2     = (const float*)d_in[3];
  const float* ls     = (const float*)d_in[4];
  const float* ld     = (const float*)d_in[5];
  const float* cp     = (const float*)d_in[6];
  const float* fc     = (const float*)d_in[7];
  const float* bv     = (const float*)d_in[8];
  const float* fb     = (const float*)d_in[9];
  float* out = (float*)d_out;
  int*   Wi  = (int*)d_ws;
  float* Wf  = (float*)d_ws;

  prep_kernel<<<dim3(2048), dim3(256), 0, stream>>>(
      roi, focals, td, t2, ls, ld, cp, fc, out, Wi, Wf);
  verts_kernel<<<dim3(NV / 128, NC), dim3(512), 0, stream>>>(
      bv, fb, Wi, Wf, out);
}

// Round 15
// 33.016 us; speedup vs baseline: 1.6577x; 1.2433x over previous
//
#include <hip/hip_runtime.h>
#include <math.h>

#define NB 128
#define NC 8
#define NV 16384
#define NK 64
#define NR 128

// flat output offsets (elements, f32)
#define OFF_MASKS  0
#define OFF_VP     2097152
#define OFF_THETAS 8388608
#define OFF_ALPHAS 8388736
#define OFF_ROT    8388864
#define OFF_SCALES 8389376
#define OFF_DEPTHS 8389504
#define OFF_C2D    8389632
#define OFF_TRANS  8389888
#define OFF_CLP    8390272

#define PI_F     3.14159265358979323846f
#define TWOPI_F  6.28318530717958647692f

// d_ws layout:
//   Wi[0..8]        scnt: class prefix over records
//   Wi[16..24]      cts:  class prefix over col-tiles (ceil(n_c/5) each)
//   Wi[32+r]        record -> batch id (class-sorted, r = 0..127)
//   Wf[256+r*8]     params per record: scale, c2=1-2qy^2, s2=2qw*qy, tx,ty,tz,feff,pad
//   Wf[1280...]     Bpack (ushort): per (coltile t, kstep ks): 512 bf16
//                   elem (t*2+ks)*512 + lane*8 + j <-> B[col=lane&15][k=ks*32+(lane>>4)*8+j]

typedef short  short8 __attribute__((ext_vector_type(8)));
typedef float  f32x4  __attribute__((ext_vector_type(4)));

__device__ __forceinline__ unsigned short f2bf(float f) {
  unsigned int u = __float_as_uint(f);
  unsigned int r = (u + 0x7FFFu + ((u >> 16) & 1u)) >> 16;   // RNE
  return (unsigned short)r;
}

// ---- kernel 1: mask zero-fill (all 2048 blocks) + scalars + B-pack ----------
__global__ __launch_bounds__(256) void prep_kernel(
    const float* __restrict__ roi, const float* __restrict__ focals,
    const float* __restrict__ td,  const float* __restrict__ t2,
    const float* __restrict__ ls,  const float* __restrict__ ld,
    const float* __restrict__ cp,  const float* __restrict__ fc,
    float* __restrict__ out, int* __restrict__ Wi, float* __restrict__ Wf) {
  int tid = threadIdx.x;
  int bx  = blockIdx.x;
  {
    // zero the whole mask region: 2048 blocks * 256 threads * 1 float4
    int i = bx * 256 + tid;
    float4 z; z.x = 0.0f; z.y = 0.0f; z.z = 0.0f; z.w = 0.0f;
    ((float4*)(out + OFF_MASKS))[i] = z;
  }
  if (bx > 16) return;

  __shared__ int cls_sh[NB];
  __shared__ int rb_sh[NB];
  __shared__ int scnt_sh[NC + 1];
  __shared__ int cts_sh[NC + 1];
  __shared__ int tcls_sh[40];   // t -> class LUT (<= 34 col-tiles)

  int b = tid;
  int cls = 0;
  if (b < NB) {
    float pmax = cp[b * NC];
    for (int c = 1; c < NC; ++c) {
      float pv = cp[b * NC + c];
      if (pv > pmax) { pmax = pv; cls = c; }
    }
    cls_sh[b] = cls;
  }
  __syncthreads();
  if (tid <= NC) {
    int cnt = 0;
    for (int j = 0; j < NB; ++j) cnt += (cls_sh[j] < tid);
    scnt_sh[tid] = cnt;
  }
  __syncthreads();
  if (tid == 0) {
    cts_sh[0] = 0;
    for (int c = 0; c < NC; ++c) {
      int n = scnt_sh[c + 1] - scnt_sh[c];
      cts_sh[c + 1] = cts_sh[c] + (n + 4) / 5;
    }
  }
  int rank = 0;
  if (b < NB) {
    rank = scnt_sh[cls];
    for (int j = 0; j < b; ++j) rank += (cls_sh[j] == cls);
    rb_sh[rank] = b;
  }
  __syncthreads();

  if (bx == 0) {
    if (b < NB) {
      float r0 = roi[b * 4 + 0], r1 = roi[b * 4 + 1];
      float r2 = roi[b * 4 + 2], r3 = roi[b * 4 + 3];
      float dx = r2 - r0, dy = r3 - r1;
      float mx = 0.5f * (r2 + r0), my = 0.5f * (r3 + r1);
      float theta = atan2f(td[b * 2 + 1], td[b * 2 + 0]);
      float qw = cosf(0.5f * theta);
      float qy = sinf(0.5f * theta);
      float area  = dx * dy;
      float scale = expf(ls[b]);
      float depth = sqrtf(expf(ld[b]) / area);
      float cx = mx + t2[b * 2 + 0] * dx;
      float cy = my + t2[b * 2 + 1] * dy;
      float tux = cy, tuy = -cx;
      float n = sqrtf(tux * tux + tuy * tuy + 1.0f);
      float tx_ = depth * (tux / n);
      float ty_ = depth * (tuy / n);
      float tz_ = depth * (-1.0f / n);
      float alpha = -(theta - atanf(tx_ / tz_));
      float a  = alpha + PI_F;
      float rr = fmodf(a, TWOPI_F);
      if (rr < 0.0f) rr += TWOPI_F;
      float alpha_out = rr - PI_F;
      float pmax = cp[b * NC];
      for (int c = 1; c < NC; ++c) pmax = fmaxf(pmax, cp[b * NC + c]);
      float feff = 2.0f * focals[b] / (float)NR;

      out[OFF_THETAS + b]      = theta;
      out[OFF_ALPHAS + b]      = alpha_out;
      out[OFF_ROT + 4 * b + 0] = qw;
      out[OFF_ROT + 4 * b + 1] = 0.0f;
      out[OFF_ROT + 4 * b + 2] = qy;
      out[OFF_ROT + 4 * b + 3] = 0.0f;
      out[OFF_SCALES + b]      = scale;
      out[OFF_DEPTHS + b]      = depth;
      out[OFF_C2D + 2 * b + 0] = cx;
      out[OFF_C2D + 2 * b + 1] = cy;
      out[OFF_TRANS + 3 * b + 0] = tx_;
      out[OFF_TRANS + 3 * b + 1] = ty_;
      out[OFF_TRANS + 3 * b + 2] = tz_;
      out[OFF_CLP + b]         = logf(pmax);

      float* par = Wf + 256 + rank * 8;
      par[0] = scale;
      par[1] = 1.0f - 2.0f * qy * qy;   // c2
      par[2] = 2.0f * qw * qy;          // s2
      par[3] = tx_;
      par[4] = ty_;   par[5] = tz_; par[6] = feff; par[7] = 0.0f;
      Wi[32 + rank] = b;
    }
    if (tid <= NC) {
      Wi[tid]      = scnt_sh[tid];
      Wi[16 + tid] = cts_sh[tid];
    }
  } else {
    // blocks 1..16: pack coeffs into bf16 B-fragments (short8 per thread)
    unsigned short* BPu = (unsigned short*)(Wf + 1280);
    int ntt = cts_sh[NC];
    if (tid < ntt) {
      int cc = 0;
      while (!(tid >= cts_sh[cc] && tid < cts_sh[cc + 1])) ++cc;
      tcls_sh[tid] = cc;
    }
    __syncthreads();
    int total8 = ntt * 128;              // 8-element groups
    for (int g8 = (bx - 1) * 256 + tid; g8 < total8; g8 += 16 * 256) {
      int t   = g8 >> 7;
      int r7  = g8 & 127;
      int ks  = r7 >> 6;
      int li  = r7 & 63;
      int col = li & 15, kg = li >> 4;
      int c   = tcls_sh[t];
      int local_ct = t - cts_sh[c];
      int n_c = scnt_sh[c + 1] - scnt_sh[c];
      short8 v8 = {0, 0, 0, 0, 0, 0, 0, 0};
      if (col < 15) {
        int lr = col / 3, comp = col - 3 * lr;
        int lrec = local_ct * 5 + lr;
        if (lrec < n_c) {
          int bb = rb_sh[scnt_sh[c] + lrec];
          const float* src =
              fc + ((size_t)(bb * NC + c) * NK + ks * 32 + kg * 8) * 3 + comp;
#pragma unroll
          for (int j = 0; j < 8; ++j) v8[j] = (short)f2bf(src[j * 3]);
        }
      }
      *(short8*)&BPu[(size_t)g8 * 8] = v8;
    }
  }
}

// ---- kernel 2: per-class GEMM + comp-specialized epilogue + fused scatter ---
// grid (128, 8): x = 128-vertex super-tile, y = class. 8 waves/block.
// vp is write-only (mask fused) -> non-temporal stores.
__global__ __launch_bounds__(512) void verts_kernel(
    const float* __restrict__ basev,    // (C, V, 3)
    const float* __restrict__ basis,    // (C, V, K)
    const int*   __restrict__ Wi,
    const float* __restrict__ Wf,
    float* __restrict__ out) {
  int c   = blockIdx.y;
  int ct0 = Wi[16 + c], ct1 = Wi[16 + c + 1];
  if (ct0 >= ct1) return;
  int rec0  = Wi[c];
  int nrecs = Wi[c + 1] - rec0;

  __shared__ float s_vp[8][256];             // per-wave store staging (8 KB)

  int wave = threadIdx.x >> 6;
  int lane = threadIdx.x & 63;
  int v0   = blockIdx.x * 128 + wave * 16;
  int row  = lane & 15, kg = lane >> 4;

  // A fragments: basis[c][v0+row][k], k = ks*32 + kg*8 + j   (f32 -> bf16)
  const float* ab = basis + ((size_t)c * NV + (v0 + row)) * NK + kg * 8;
  float4 a0 = *(const float4*)(ab);
  float4 a1 = *(const float4*)(ab + 4);
  float4 a2 = *(const float4*)(ab + 32);
  float4 a3 = *(const float4*)(ab + 36);
  short8 A0, A1;
  A0[0]=f2bf(a0.x); A0[1]=f2bf(a0.y); A0[2]=f2bf(a0.z); A0[3]=f2bf(a0.w);
  A0[4]=f2bf(a1.x); A0[5]=f2bf(a1.y); A0[6]=f2bf(a1.z); A0[7]=f2bf(a1.w);
  A1[0]=f2bf(a2.x); A1[1]=f2bf(a2.y); A1[2]=f2bf(a2.z); A1[3]=f2bf(a2.w);
  A1[4]=f2bf(a3.x); A1[5]=f2bf(a3.y); A1[6]=f2bf(a3.z); A1[7]=f2bf(a3.w);

  // epilogue lane roles: q -> (record lr, component comp); rowg -> vertex group
  int q = lane & 15, rowg = lane >> 4;
  int lr = q / 3, comp = q - 3 * lr;
  bool qok = (q < 15);
  // per-lane base-vertex component (own comp only)
  float bvo[4];
#pragma unroll
  for (int j = 0; j < 4; ++j)
    bvo[j] = basev[((size_t)c * NV + (v0 + rowg * 4 + j)) * 3 + (qok ? comp : 0)];
  int sbase = lane & 48;
  int sxi = sbase | (qok ? 3 * lr     : 0);   // x-lane of my record
  int syi = sbase | (qok ? 3 * lr + 1 : 0);   // y-lane of my record
  int szi = sbase | (qok ? 3 * lr + 2 : 0);   // z-lane of my record
  // round-1 partner: x pulls vz, z pulls vx, y pulls self
  int pull1 = (comp == 0) ? szi : ((comp == 2) ? sxi : lane);
  // round-2: x,y pull inv from z-lane; z pulls self
  int pull2 = (comp == 2) ? lane : szi;
  // round-3 (mask): x pulls py from y-lane; others pull self (unused)
  int pull3 = (comp == 0) ? syi : lane;

  // readout lane roles
  int rrec = lane / 12;            // 0..4 (lanes >= 60 idle)
  int roff = (lane % 12) * 4;      // float4 offset within the record's 48

  const float4* BP4 = (const float4*)(Wf + 1280);

  for (int t = ct0; t < ct1; ++t) {
    float4 rb0 = BP4[(size_t)(t * 2 + 0) * 64 + lane];
    float4 rb1 = BP4[(size_t)(t * 2 + 1) * 64 + lane];
    short8 B0 = *(short8*)&rb0;
    short8 B1 = *(short8*)&rb1;
    f32x4 acc = {0.0f, 0.0f, 0.0f, 0.0f};
    acc = __builtin_amdgcn_mfma_f32_16x16x32_bf16(A0, B0, acc, 0, 0, 0);
    acc = __builtin_amdgcn_mfma_f32_16x16x32_bf16(A1, B1, acc, 0, 0, 0);

    int nrec_ct = nrecs - (t - ct0) * 5;
    nrec_ct = (nrec_ct > 5) ? 5 : nrec_ct;
    bool valid = qok && (lr < nrec_ct);
    int rec = rec0 + (t - ct0) * 5 + (valid ? lr : 0);
    int bb  = Wi[32 + rec];
    float4 P0 = *(const float4*)(Wf + 256 + rec * 8);
    float4 P1 = *(const float4*)(Wf + 256 + rec * 8 + 4);
    float scale = P0.x, c2 = P0.y, s2 = P0.z, tx = P0.w;
    float ty = P1.x, tz = P1.y, feff = P1.z;
    // per-lane translation
    float tro = (comp == 0) ? tx : ((comp == 1) ? ty : tz);

#pragma unroll
    for (int j = 0; j < 4; ++j) {
      float vown = (bvo[j] + acc[j]) * scale;
      float vpart = __shfl(vown, pull1);
      // w = own world component:
      //   x: vx*c2 + s2*vz + tx ;  y: vy + ty ;  z: vz*c2 - s2*vx + tz
      float rot = (comp == 1) ? vown
                : fmaf(vown, c2, (comp == 0) ? s2 * vpart : -s2 * vpart);
      float w = rot + tro;
      // z-lane computes inv; others pull it
      float zsafe = (w > -1e-4f) ? -1e-4f : w;
      float invz  = feff / (-zsafe);
      float invp  = __shfl(invz, pull2);
      float ov = (comp == 2) ? -w : (w * invp * 0.5f + 0.5f) * (float)NR;
      if (qok) s_vp[wave][lr * 48 + (rowg * 4 + j) * 3 + comp] = ov;
      // fused mask scatter: x-lane has px=ov, pulls py from y-lane
      float pyv = __shfl(ov, pull3);
      if (valid && comp == 0) {
        int xi = (int)fminf(fmaxf(ov,  0.0f), 127.0f);
        int yi = (int)fminf(fmaxf(pyv, 0.0f), 127.0f);
        out[OFF_MASKS + (bb << 14) + yi * NR + xi] = 1.0f;
      }
    }
    // in-order per-wave DS: reads below see the writes above (no barrier)
    if (lane < 60 && rrec < nrec_ct) {
      f32x4 val = *(f32x4*)&s_vp[wave][rrec * 48 + roff];
      int rrec_g = rec0 + (t - ct0) * 5 + rrec;
      int bb2 = Wi[32 + rrec_g];
      __builtin_nontemporal_store(
          val, (f32x4*)&out[OFF_VP + ((size_t)bb2 * NV + v0) * 3 + roff]);
    }
  }
}

extern "C" void kernel_launch(void* const* d_in, const int* in_sizes, int n_in,
                              void* d_out, int out_size, void* d_ws, size_t ws_size,
                              hipStream_t stream) {
  const float* roi    = (const float*)d_in[0];
  const float* focals = (const float*)d_in[1];
  const float* td     = (const float*)d_in[2];
  const float* t2     = (const float*)d_in[3];
  const float* ls     = (const float*)d_in[4];
  const float* ld     = (const float*)d_in[5];
  const float* cp     = (const float*)d_in[6];
  const float* fc     = (const float*)d_in[7];
  const float* bv     = (const float*)d_in[8];
  const float* fb     = (const float*)d_in[9];
  float* out = (float*)d_out;
  int*   Wi  = (int*)d_ws;
  float* Wf  = (float*)d_ws;

  prep_kernel<<<dim3(2048), dim3(256), 0, stream>>>(
      roi, focals, td, t2, ls, ld, cp, fc, out, Wi, Wf);
  verts_kernel<<<dim3(NV / 128, NC), dim3(512), 0, stream>>>(
      bv, fb, Wi, Wf, out);
}